// Round 1
// 17823.083 us; speedup vs baseline: 1.0109x; 1.0109x over previous
//
#include <hip/hip_runtime.h>
#include <math.h>

#define L_SEQ 500
#define NBS   512
#define N     64
#define NI    32
#define AUGW  132   // Aug row stride: cols 0..63 S(lower), 64..127 E, 128 z, 129..131 pad(0)
#define PW    68    // P row stride
#define HW    68    // H row stride

// LDS layout (floats); every array base and row stride is 16B aligned
#define OFF_AUG 0
#define OFF_P   (OFF_AUG + 64*AUGW)   //  8448
#define OFF_H   (OFF_P   + 64*PW)     // 12800
#define OFF_BT  (OFF_H   + 64*HW)     // 17152  (B transposed: Bt[k*64+i] = B[i][k])
#define OFF_RK  (OFF_BT  + NI*64)     // 19200
#define OFF_QD  (OFF_RK  + 64)
#define OFF_RD  (OFF_QD  + 64)
#define OFF_MU  (OFF_RD  + 64)
#define OFF_MUP (OFF_MU  + 64)
#define OFF_WV  (OFF_MUP + 64)
#define OFF_U   (OFF_WV  + 64)
#define OFF_YV  (OFF_U   + 32)        // prefetched observation row (64 floats)
#define SM_FLOATS (OFF_YV + 64)       // 19680 floats = 78720 B -> 2 blocks/CU

union F4 { float4 v; float f[4]; };

// Lw (true L factors) overlaid in Aug's strict upper triangle: row i (i in [16,64))
// lives at Aug[(i-16)*AUGW + 48 + k], k in [0,16).
#define LW(i,k) Aug[((i)-16)*AUGW + 48 + (k)]

__global__ __launch_bounds__(256, 2)
void akf3(const float* __restrict__ ext,   // (500,512,32)
          const float* __restrict__ obs,   // (500,512,64)
          const float* __restrict__ mu0,   // (512,64)
          const float* __restrict__ sg0,   // (512,64)
          const float* __restrict__ lsg,   // (64)
          const float* __restrict__ Bm,    // (64,32)
          const float* __restrict__ Hm,    // (64,64)
          const float* __restrict__ ldl,   // (64)
          float* __restrict__ out_mu,      // (500,512,64)
          float* __restrict__ out_ls)      // (500,512,64)
{
    extern __shared__ float sm[];
    float* Aug = sm + OFF_AUG;
    float* P   = sm + OFF_P;
    float* Hs  = sm + OFF_H;
    float* Bt  = sm + OFF_BT;
    float* rk  = sm + OFF_RK;
    float* Qd  = sm + OFF_QD;
    float* Rd  = sm + OFF_RD;
    float* mu  = sm + OFF_MU;
    float* mup = sm + OFF_MUP;
    float* wv  = sm + OFF_WV;
    float* uvec= sm + OFF_U;
    float* yv  = sm + OFF_YV;

    const int b   = blockIdx.x;
    const int tid = threadIdx.x;
    const int tx  = tid & 15;
    const int ty  = tid >> 4;

    // packed lower-incl-diag 16x16 tile map for tid<136 (used by phases e,g)
    int Rlow = 0, Clow = 0;
    {
        int t = tid < 136 ? tid : 0;
        int R = (int)((sqrtf(8.0f * (float)t + 1.0f) - 1.0f) * 0.5f);
        if ((R + 1) * (R + 2) / 2 <= t) ++R;
        if (R * (R + 1) / 2 > t) --R;
        Rlow = R; Clow = t - R * (R + 1) / 2;
    }

    // ---------------- init ----------------
    if (tid < 64) {
        int i = tid;
        float q = expf(lsg[i]); Qd[i] = q * q;
        float r = expf(ldl[i]); Rd[i] = r * r;
        float m0 = mu0[b * N + i];
        float s0 = sg0[b * N + i];
        mu[i]  = m0;
        mup[i] = s0;                       // temp: sigma0
        out_mu[(size_t)b * N + i] = m0;
        out_ls[(size_t)b * N + i] = logf(s0);
        Aug[i * AUGW + 129] = 0.f; Aug[i * AUGW + 130] = 0.f; Aug[i * AUGW + 131] = 0.f;
    }
    for (int e = tid; e < N * N; e += 256) {
        Hs[(e >> 6) * HW + (e & 63)] = Hm[e];
    }
    for (int e = tid; e < N * NI; e += 256) {
        int i = e >> 5, k = e & 31;
        Bt[k * 64 + i] = Bm[e];
    }
    __syncthreads();
    for (int e = tid; e < N * N; e += 256) {
        int i = e >> 6, j = e & 63;
        float v = 0.f;
        if (i == j) { float s = mup[i]; v = s * s; }
        P[i * PW + j] = v;
    }
    if (tid >= 192 && tid < 200) {     // stage u for s=0
        int q = tid - 192;
        *(float4*)&uvec[4 * q] = *(const float4*)&ext[(size_t)b * NI + 4 * q];
    }
    if (tid >= 200 && tid < 216) {     // stage y for s=0 (obs row 1)
        int q = tid - 200;
        *(float4*)&yv[4 * q] = *(const float4*)&obs[(size_t)(NBS + b) * N + 4 * q];
    }
    __syncthreads();

    // ---------------- time loop ----------------
    #pragma unroll 1
    for (int s = 0; s < L_SEQ - 1; ++s) {
        // ---- Phase D: E = H * (P + Q) on all 256 threads.
        //      Wave-0 prologue (wave-synchronous): mu_pred, innov.
        if (tid < 64) {
            float acc = mu[tid];
            #pragma unroll
            for (int k = 0; k < NI; ++k) acc += Bt[k * 64 + tid] * uvec[k];
            mup[tid] = acc;
        }
        __builtin_amdgcn_wave_barrier();
        if (tid < 64) {
            float acc = yv[tid];                          // prefetched obs(s+1)
            #pragma unroll 4
            for (int c4 = 0; c4 < 16; ++c4) {
                F4 h; h.v = *(const float4*)&Hs[tid * HW + 4 * c4];
                F4 m; m.v = *(const float4*)&mup[4 * c4];
                acc -= h.f[0]*m.f[0] + h.f[1]*m.f[1] + h.f[2]*m.f[2] + h.f[3]*m.f[3];
            }
            Aug[tid * AUGW + 128] = acc;
        }
        {
            const int i0 = 4 * ty, j0 = 4 * tx;
            float acc[4][4];
            // Q folded into E: E = H*P + H*diag(Q); P diag itself updated in phase E
            F4 qv; qv.v = *(const float4*)&Qd[j0];
            #pragma unroll
            for (int dr = 0; dr < 4; ++dr) {
                F4 hv; hv.v = *(const float4*)&Hs[(i0 + dr) * HW + j0];
                #pragma unroll
                for (int dc = 0; dc < 4; ++dc) acc[dr][dc] = hv.f[dc] * qv.f[dc];
            }
            #pragma unroll 4
            for (int c4 = 0; c4 < 16; ++c4) {
                F4 h4[4], p4[4];
                #pragma unroll
                for (int dr = 0; dr < 4; ++dr) h4[dr].v = *(const float4*)&Hs[(i0 + dr) * HW + 4 * c4];
                #pragma unroll
                for (int dk = 0; dk < 4; ++dk) p4[dk].v = *(const float4*)&P[(4 * c4 + dk) * PW + j0];
                #pragma unroll
                for (int dk = 0; dk < 4; ++dk)
                    #pragma unroll
                    for (int dr = 0; dr < 4; ++dr)
                        #pragma unroll
                        for (int dc = 0; dc < 4; ++dc)
                            acc[dr][dc] += h4[dr].f[dk] * p4[dk].f[dc];
            }
            #pragma unroll
            for (int dr = 0; dr < 4; ++dr) {
                float4 v; v.x = acc[dr][0]; v.y = acc[dr][1]; v.z = acc[dr][2]; v.w = acc[dr][3];
                *(float4*)&Aug[(i0 + dr) * AUGW + 64 + j0] = v;
            }
        }
        __syncthreads();

        // ---- Phase E: S lower = E * H^T + R (tid<136); P diag += Q (tid 136..199)
        if (tid < 136) {
            const int i0 = 4 * Rlow, j0 = 4 * Clow;
            float acc[4][4];
            #pragma unroll
            for (int a = 0; a < 4; ++a)
                #pragma unroll
                for (int c = 0; c < 4; ++c) acc[a][c] = 0.f;
            #pragma unroll 4
            for (int c4 = 0; c4 < 16; ++c4) {
                F4 a4[4], b4[4];
                #pragma unroll
                for (int dr = 0; dr < 4; ++dr) a4[dr].v = *(const float4*)&Aug[(i0 + dr) * AUGW + 64 + 4 * c4];
                #pragma unroll
                for (int dc = 0; dc < 4; ++dc) b4[dc].v = *(const float4*)&Hs[(j0 + dc) * HW + 4 * c4];
                #pragma unroll
                for (int dr = 0; dr < 4; ++dr)
                    #pragma unroll
                    for (int dc = 0; dc < 4; ++dc)
                        #pragma unroll
                        for (int dk = 0; dk < 4; ++dk)
                            acc[dr][dc] += a4[dr].f[dk] * b4[dc].f[dk];
            }
            #pragma unroll
            for (int dr = 0; dr < 4; ++dr) {
                #pragma unroll
                for (int dc = 0; dc < 4; ++dc)
                    if (i0 + dr == j0 + dc) acc[dr][dc] += Rd[i0 + dr];
                float4 v; v.x = acc[dr][0]; v.y = acc[dr][1]; v.z = acc[dr][2]; v.w = acc[dr][3];
                *(float4*)&Aug[(i0 + dr) * AUGW + j0] = v;
            }
        } else if (tid < 200) {
            const int i = tid - 136;
            P[i * PW + i] += Qd[i];        // P becomes P_pred; read by phase G
        }
        __syncthreads();

        // ---- (f) blocked LDL^T: 4 panels of 16 pivots
        #pragma unroll 1
        for (int p = 0; p < 4; ++p) {
            const int p0 = 16 * p;
            if (tid < 64) {
                // F1: panel factor (wave 0, wave-synchronous, registers + shfl)
                const int lane = tid;
                float st[16], lw[16], myrk = 0.f;
                if (lane >= p0) {
                    #pragma unroll
                    for (int q = 0; q < 4; ++q) {
                        F4 t4; t4.v = *(const float4*)&Aug[lane * AUGW + p0 + 4 * q];
                        st[4*q+0] = t4.f[0]; st[4*q+1] = t4.f[1]; st[4*q+2] = t4.f[2]; st[4*q+3] = t4.f[3];
                    }
                } else {
                    #pragma unroll
                    for (int q = 0; q < 16; ++q) st[q] = 0.f;
                }
                #pragma unroll
                for (int kr = 0; kr < 16; ++kr) {
                    const int k = p0 + kr;
                    float dk  = __shfl(st[kr], k, 64);
                    float rkv = 1.0f / dk;
                    if (lane == k) myrk = rkv;
                    float coef = st[kr] * rkv;
                    coef = (lane > k) ? coef : 0.f;
                    lw[kr] = coef;
                    #pragma unroll
                    for (int jr = kr + 1; jr < 16; ++jr) {
                        float wjk = __shfl(st[kr], p0 + jr, 64);
                        st[jr] -= coef * wjk;
                    }
                }
                if (lane >= p0) {
                    #pragma unroll
                    for (int q = 0; q < 4; ++q) {
                        float4 v; v.x = st[4*q+0]; v.y = st[4*q+1]; v.z = st[4*q+2]; v.w = st[4*q+3];
                        *(float4*)&Aug[lane * AUGW + p0 + 4 * q] = v;   // W (raw factored)
                    }
                    if (lane < p0 + 16) rk[lane] = myrk;
                }
                if (lane >= p0 + 16) {   // only trailing rows' L are ever read (by F3)
                    #pragma unroll
                    for (int q = 0; q < 4; ++q) {
                        float4 v; v.x = lw[4*q+0]; v.y = lw[4*q+1]; v.z = lw[4*q+2]; v.w = lw[4*q+3];
                        *(float4*)&LW(lane, 4 * q) = v;                 // true L factors
                    }
                }
                // F2: panel-row E/z triangular update (same wave, register col-slices)
                float ec[16], zr[16];
                #pragma unroll
                for (int r2 = 0; r2 < 16; ++r2) {
                    ec[r2] = Aug[(p0 + r2) * AUGW + 64 + lane];
                    zr[r2] = Aug[(p0 + r2) * AUGW + 128];
                }
                #pragma unroll
                for (int kp = 0; kp < 15; ++kp) {
                    #pragma unroll
                    for (int r2 = kp + 1; r2 < 16; ++r2) {
                        float L = __shfl(lw[kp], p0 + r2, 64);
                        ec[r2] -= L * ec[kp];
                        zr[r2] -= L * zr[kp];
                    }
                }
                #pragma unroll
                for (int r2 = 0; r2 < 16; ++r2)
                    Aug[(p0 + r2) * AUGW + 64 + lane] = ec[r2];
                if (lane == 0) {
                    #pragma unroll
                    for (int r2 = 0; r2 < 16; ++r2)
                        Aug[(p0 + r2) * AUGW + 128] = zr[r2];
                }
            }
            __syncthreads();

            // F3: rank-16 trailing update (empty for p==3 -> skipped, saves a barrier)
            if (p < 3) {
                const int TS  = (p == 0) ? 78 : (p == 1) ? 36 : 10;
                const int rows = 48 - 16 * p;                 // trailing rows
                const int TE  = (rows / 4) * 17;
                const int tot = TS + TE;
                const int ofs = 4 * (p + 1);
                #pragma unroll 1
                for (int t = tid; t < tot; t += 256) {
                    int i0, Cb; bool isS;
                    if (t < TS) {
                        int rr = (int)((sqrtf(8.0f * (float)t + 1.0f) - 1.0f) * 0.5f);
                        if ((rr + 1) * (rr + 2) / 2 <= t) ++rr;
                        if (rr * (rr + 1) / 2 > t) --rr;
                        int cc = t - rr * (rr + 1) / 2;
                        i0 = 4 * (ofs + rr); Cb = 4 * (ofs + cc); isS = true;
                    } else {
                        int e2 = t - TS;
                        i0 = 4 * (ofs + e2 / 17); Cb = 64 + 4 * (e2 % 17); isS = false;
                    }
                    F4 acc[4];
                    #pragma unroll
                    for (int dr = 0; dr < 4; ++dr) acc[dr].v = *(const float4*)&Aug[(i0 + dr) * AUGW + Cb];
                    #pragma unroll
                    for (int c4 = 0; c4 < 4; ++c4) {
                        F4 a4[4];
                        #pragma unroll
                        for (int dr = 0; dr < 4; ++dr) a4[dr].v = *(const float4*)&LW(i0 + dr, 4 * c4);
                        if (isS) {
                            F4 b4[4];
                            #pragma unroll
                            for (int dc = 0; dc < 4; ++dc) b4[dc].v = *(const float4*)&Aug[(Cb + dc) * AUGW + p0 + 4 * c4];
                            #pragma unroll
                            for (int dr = 0; dr < 4; ++dr)
                                #pragma unroll
                                for (int dc = 0; dc < 4; ++dc)
                                    #pragma unroll
                                    for (int dk = 0; dk < 4; ++dk)
                                        acc[dr].f[dc] -= a4[dr].f[dk] * b4[dc].f[dk];
                        } else {
                            F4 b4[4];
                            #pragma unroll
                            for (int dk = 0; dk < 4; ++dk) b4[dk].v = *(const float4*)&Aug[(p0 + 4 * c4 + dk) * AUGW + Cb];
                            #pragma unroll
                            for (int dk = 0; dk < 4; ++dk)
                                #pragma unroll
                                for (int dr = 0; dr < 4; ++dr)
                                    #pragma unroll
                                    for (int dc = 0; dc < 4; ++dc)
                                        acc[dr].f[dc] -= a4[dr].f[dk] * b4[dk].f[dc];
                        }
                    }
                    #pragma unroll
                    for (int dr = 0; dr < 4; ++dr) *(float4*)&Aug[(i0 + dr) * AUGW + Cb] = acc[dr].v;
                }
                __syncthreads();
            }
        }

        // ---- Phase G: P_post (lower + mirrored upper + out_ls from regs, tid<136);
        //      mu_post + out_mu (wave 3); stage next u/y (tid 136..159)
        const size_t o = (size_t)((s + 1) * NBS + b) * N;
        if (tid < 136) {
            const int i0 = 4 * Rlow, j0 = 4 * Clow;
            F4 acc[4];
            #pragma unroll
            for (int dr = 0; dr < 4; ++dr) acc[dr].v = *(const float4*)&P[(i0 + dr) * PW + j0];
            #pragma unroll 2
            for (int c4 = 0; c4 < 16; ++c4) {
                F4 rv; rv.v = *(const float4*)&rk[4 * c4];
                F4 ea[4], eb[4];
                #pragma unroll
                for (int dk = 0; dk < 4; ++dk) ea[dk].v = *(const float4*)&Aug[(4 * c4 + dk) * AUGW + 64 + i0];
                #pragma unroll
                for (int dk = 0; dk < 4; ++dk) eb[dk].v = *(const float4*)&Aug[(4 * c4 + dk) * AUGW + 64 + j0];
                #pragma unroll
                for (int dk = 0; dk < 4; ++dk) {
                    float sc[4];
                    #pragma unroll
                    for (int dr = 0; dr < 4; ++dr) sc[dr] = ea[dk].f[dr] * rv.f[dk];
                    #pragma unroll
                    for (int dr = 0; dr < 4; ++dr)
                        #pragma unroll
                        for (int dc = 0; dc < 4; ++dc)
                            acc[dr].f[dc] -= sc[dr] * eb[dk].f[dc];
                }
            }
            #pragma unroll
            for (int dr = 0; dr < 4; ++dr) *(float4*)&P[(i0 + dr) * PW + j0] = acc[dr].v;
            if (Rlow != Clow) {
                // mirror to upper from registers (no extra phase, no re-read)
                #pragma unroll
                for (int dc = 0; dc < 4; ++dc) {
                    float4 v; v.x = acc[0].f[dc]; v.y = acc[1].f[dc]; v.z = acc[2].f[dc]; v.w = acc[3].f[dc];
                    *(float4*)&P[(j0 + dc) * PW + i0] = v;
                }
            } else {
                #pragma unroll
                for (int dr = 0; dr < 4; ++dr)
                    out_ls[o + i0 + dr] = 0.5f * logf(acc[dr].f[dr]);
            }
        }
        if (tid >= 192) {   // mu_post = mu_pred + E~^T (rk .* z~)   (wave 3)
            const int i = tid - 192;
            wv[i] = rk[i] * Aug[i * AUGW + 128];
            float acc = mup[i];
            #pragma unroll 4
            for (int c4 = 0; c4 < 16; ++c4) {
                F4 wq; wq.v = *(const float4*)&wv[4 * c4];
                #pragma unroll
                for (int dk = 0; dk < 4; ++dk)
                    acc += Aug[(4 * c4 + dk) * AUGW + 64 + i] * wq.f[dk];
            }
            mu[i] = acc;
            out_mu[o + i] = acc;
        }
        if (tid >= 136 && tid < 144) {          // stage u for s+1
            int q = tid - 136;
            *(float4*)&uvec[4 * q] = *(const float4*)&ext[(size_t)((s + 1) * NBS + b) * NI + 4 * q];
        }
        if (tid >= 144 && tid < 160 && s < L_SEQ - 2) {   // stage y for s+1 (obs row s+2)
            int q = tid - 144;
            *(float4*)&yv[4 * q] = *(const float4*)&obs[(size_t)((s + 2) * NBS + b) * N + 4 * q];
        }
        __syncthreads();
    }
}

extern "C" void kernel_launch(void* const* d_in, const int* in_sizes, int n_in,
                              void* d_out, int out_size, void* d_ws, size_t ws_size,
                              hipStream_t stream) {
    const float* ext = (const float*)d_in[0];
    const float* obs = (const float*)d_in[1];
    const float* mu0 = (const float*)d_in[2];
    const float* sg0 = (const float*)d_in[3];
    const float* lsg = (const float*)d_in[4];
    const float* Bm  = (const float*)d_in[5];
    const float* Hm  = (const float*)d_in[6];
    const float* ldl = (const float*)d_in[7];
    float* out_mu = (float*)d_out;
    float* out_ls = out_mu + (size_t)L_SEQ * NBS * N;

    size_t smem = (size_t)SM_FLOATS * sizeof(float);   // 78720 B
    hipFuncSetAttribute(reinterpret_cast<const void*>(akf3),
                        hipFuncAttributeMaxDynamicSharedMemorySize, (int)smem);

    akf3<<<dim3(NBS), dim3(256), smem, stream>>>(
        ext, obs, mu0, sg0, lsg, Bm, Hm, ldl, out_mu, out_ls);
}

// Round 3
// 14878.136 us; speedup vs baseline: 1.2110x; 1.1979x over previous
//
#include <hip/hip_runtime.h>
#include <math.h>

#define L_SEQ 500
#define NBS   512
#define N     64
#define NI    32
#define AUGW  132   // Aug row stride: cols 0..63 S(lower), 64..127 E, 128 z, 129..131 pad(0)
#define PW    68    // P row stride
#define HW    68    // H row stride

// LDS layout (floats); every array base and row stride is 16B aligned
#define OFF_AUG 0
#define OFF_P   (OFF_AUG + 64*AUGW)   //  8448
#define OFF_H   (OFF_P   + 64*PW)     // 12800
#define OFF_BT  (OFF_H   + 64*HW)     // 17152  (B transposed: Bt[k*64+i] = B[i][k])
#define OFF_RK  (OFF_BT  + NI*64)     // 19200
#define OFF_QD  (OFF_RK  + 64)
#define OFF_RD  (OFF_QD  + 64)
#define OFF_MU  (OFF_RD  + 64)
#define OFF_MUP (OFF_MU  + 64)
#define OFF_WV  (OFF_MUP + 64)
#define OFF_U   (OFF_WV  + 64)
#define OFF_YV  (OFF_U   + 32)        // prefetched observation row (64 floats)
#define OFF_LSC (OFF_YV  + 64)        // frozen out_ls vector (converged mode)
#define OFF_FLG (OFF_LSC + 64)        // [0]=dmax bits, [1]=pmax bits (int)
#define SM_FLOATS (OFF_FLG + 4)       // 19748 floats = 78992 B -> 2 blocks/CU

#define CONV_TAU  2e-5f
#define CONV_MINS 20

union F4 { float4 v; float f[4]; };

// Lw (true L factors) overlaid in Aug's strict upper triangle: row i (i in [16,64))
// lives at Aug[(i-16)*AUGW + 48 + k], k in [0,16).
#define LW(i,k) Aug[((i)-16)*AUGW + 48 + (k)]

__global__ __launch_bounds__(256, 2)
void akf5(const float* __restrict__ ext,   // (500,512,32)
          const float* __restrict__ obs,   // (500,512,64)
          const float* __restrict__ mu0,   // (512,64)
          const float* __restrict__ sg0,   // (512,64)
          const float* __restrict__ lsg,   // (64)
          const float* __restrict__ Bm,    // (64,32)
          const float* __restrict__ Hm,    // (64,64)
          const float* __restrict__ ldl,   // (64)
          float* __restrict__ out_mu,      // (500,512,64)
          float* __restrict__ out_ls)      // (500,512,64)
{
    extern __shared__ float sm[];
    float* Aug = sm + OFF_AUG;
    float* P   = sm + OFF_P;
    float* Hs  = sm + OFF_H;
    float* Bt  = sm + OFF_BT;
    float* rk  = sm + OFF_RK;
    float* Qd  = sm + OFF_QD;
    float* Rd  = sm + OFF_RD;
    float* mu  = sm + OFF_MU;
    float* mup = sm + OFF_MUP;
    float* wv  = sm + OFF_WV;
    float* uvec= sm + OFF_U;
    float* yv  = sm + OFF_YV;
    float* lsc = sm + OFF_LSC;
    int*   flagI = (int*)(sm + OFF_FLG);

    const int b   = blockIdx.x;
    const int tid = threadIdx.x;
    const int tx  = tid & 15;
    const int ty  = tid >> 4;

    // packed lower-incl-diag 16x16 tile map for tid<136 (used by phases e,g)
    int Rlow = 0, Clow = 0;
    {
        int t = tid < 136 ? tid : 0;
        int R = (int)((sqrtf(8.0f * (float)t + 1.0f) - 1.0f) * 0.5f);
        if ((R + 1) * (R + 2) / 2 <= t) ++R;
        if (R * (R + 1) / 2 > t) --R;
        Rlow = R; Clow = t - R * (R + 1) / 2;
    }

    // ---------------- init ----------------
    if (tid < 64) {
        int i = tid;
        float q = expf(lsg[i]); Qd[i] = q * q;
        float r = expf(ldl[i]); Rd[i] = r * r;
        float m0 = mu0[b * N + i];
        float s0 = sg0[b * N + i];
        mu[i]  = m0;
        mup[i] = s0;                       // temp: sigma0
        out_mu[(size_t)b * N + i] = m0;
        out_ls[(size_t)b * N + i] = logf(s0);
        Aug[i * AUGW + 129] = 0.f; Aug[i * AUGW + 130] = 0.f; Aug[i * AUGW + 131] = 0.f;
    }
    if (tid == 0) { flagI[0] = 0; flagI[1] = 0; }
    for (int e = tid; e < N * N; e += 256) {
        Hs[(e >> 6) * HW + (e & 63)] = Hm[e];
    }
    for (int e = tid; e < N * NI; e += 256) {
        int i = e >> 5, k = e & 31;
        Bt[k * 64 + i] = Bm[e];
    }
    __syncthreads();
    for (int e = tid; e < N * N; e += 256) {
        int i = e >> 6, j = e & 63;
        float v = 0.f;
        if (i == j) { float s = mup[i]; v = s * s; }
        P[i * PW + j] = v;
    }
    if (tid >= 192 && tid < 200) {     // stage u for s=0
        int q = tid - 192;
        *(float4*)&uvec[4 * q] = *(const float4*)&ext[(size_t)b * NI + 4 * q];
    }
    if (tid >= 200 && tid < 216) {     // stage y for s=0 (obs row 1)
        int q = tid - 200;
        *(float4*)&yv[4 * q] = *(const float4*)&obs[(size_t)(NBS + b) * N + 4 * q];
    }
    __syncthreads();

    int streak = 0, sb = 0;

    // ---------------- full time loop (until covariance converges) ----------------
    #pragma unroll 1
    for (int s = 0; s < L_SEQ - 1; ++s) {
        // ---- Phase D: E = H * (P + Q) on all 256 threads.
        //      Wave-0 prologue (wave-synchronous): mu_pred, innov.
        if (tid < 64) {
            float acc = mu[tid];
            #pragma unroll
            for (int k = 0; k < NI; ++k) acc += Bt[k * 64 + tid] * uvec[k];
            mup[tid] = acc;
        }
        __builtin_amdgcn_wave_barrier();
        if (tid < 64) {
            float acc = yv[tid];                          // prefetched obs(s+1)
            #pragma unroll 4
            for (int c4 = 0; c4 < 16; ++c4) {
                F4 h; h.v = *(const float4*)&Hs[tid * HW + 4 * c4];
                F4 m; m.v = *(const float4*)&mup[4 * c4];
                acc -= h.f[0]*m.f[0] + h.f[1]*m.f[1] + h.f[2]*m.f[2] + h.f[3]*m.f[3];
            }
            Aug[tid * AUGW + 128] = acc;
        }
        {
            const int i0 = 4 * ty, j0 = 4 * tx;
            float acc[4][4];
            // Q folded into E: E = H*P + H*diag(Q); P diag itself updated in phase E
            F4 qv; qv.v = *(const float4*)&Qd[j0];
            #pragma unroll
            for (int dr = 0; dr < 4; ++dr) {
                F4 hv; hv.v = *(const float4*)&Hs[(i0 + dr) * HW + j0];
                #pragma unroll
                for (int dc = 0; dc < 4; ++dc) acc[dr][dc] = hv.f[dc] * qv.f[dc];
            }
            #pragma unroll 4
            for (int c4 = 0; c4 < 16; ++c4) {
                F4 h4[4], p4[4];
                #pragma unroll
                for (int dr = 0; dr < 4; ++dr) h4[dr].v = *(const float4*)&Hs[(i0 + dr) * HW + 4 * c4];
                #pragma unroll
                for (int dk = 0; dk < 4; ++dk) p4[dk].v = *(const float4*)&P[(4 * c4 + dk) * PW + j0];
                #pragma unroll
                for (int dk = 0; dk < 4; ++dk)
                    #pragma unroll
                    for (int dr = 0; dr < 4; ++dr)
                        #pragma unroll
                        for (int dc = 0; dc < 4; ++dc)
                            acc[dr][dc] += h4[dr].f[dk] * p4[dk].f[dc];
            }
            #pragma unroll
            for (int dr = 0; dr < 4; ++dr) {
                float4 v; v.x = acc[dr][0]; v.y = acc[dr][1]; v.z = acc[dr][2]; v.w = acc[dr][3];
                *(float4*)&Aug[(i0 + dr) * AUGW + 64 + j0] = v;
            }
        }
        __syncthreads();

        // ---- Phase E: S lower = E * H^T + R (tid<136); P diag += Q (tid 136..199);
        //      reset convergence flags (tid 200)
        if (tid < 136) {
            const int i0 = 4 * Rlow, j0 = 4 * Clow;
            float acc[4][4];
            #pragma unroll
            for (int a = 0; a < 4; ++a)
                #pragma unroll
                for (int c = 0; c < 4; ++c) acc[a][c] = 0.f;
            #pragma unroll 4
            for (int c4 = 0; c4 < 16; ++c4) {
                F4 a4[4], b4[4];
                #pragma unroll
                for (int dr = 0; dr < 4; ++dr) a4[dr].v = *(const float4*)&Aug[(i0 + dr) * AUGW + 64 + 4 * c4];
                #pragma unroll
                for (int dc = 0; dc < 4; ++dc) b4[dc].v = *(const float4*)&Hs[(j0 + dc) * HW + 4 * c4];
                #pragma unroll
                for (int dr = 0; dr < 4; ++dr)
                    #pragma unroll
                    for (int dc = 0; dc < 4; ++dc)
                        #pragma unroll
                        for (int dk = 0; dk < 4; ++dk)
                            acc[dr][dc] += a4[dr].f[dk] * b4[dc].f[dk];
            }
            #pragma unroll
            for (int dr = 0; dr < 4; ++dr) {
                #pragma unroll
                for (int dc = 0; dc < 4; ++dc)
                    if (i0 + dr == j0 + dc) acc[dr][dc] += Rd[i0 + dr];
                float4 v; v.x = acc[dr][0]; v.y = acc[dr][1]; v.z = acc[dr][2]; v.w = acc[dr][3];
                *(float4*)&Aug[(i0 + dr) * AUGW + j0] = v;
            }
        } else if (tid < 200) {
            const int i = tid - 136;
            P[i * PW + i] += Qd[i];        // P becomes P_pred; read by phase G
        } else if (tid == 200) {
            flagI[0] = 0; flagI[1] = 0;    // reset for this step's phase-G atomics
        }
        __syncthreads();

        // ---- (f) blocked LDL^T: 4 panels of 16 pivots
        #pragma unroll 1
        for (int p = 0; p < 4; ++p) {
            const int p0 = 16 * p;
            if (tid < 64) {
                // F1: panel factor (wave 0, wave-synchronous, registers + shfl)
                const int lane = tid;
                float st[16], lw[16], myrk = 0.f;
                if (lane >= p0) {
                    #pragma unroll
                    for (int q = 0; q < 4; ++q) {
                        F4 t4; t4.v = *(const float4*)&Aug[lane * AUGW + p0 + 4 * q];
                        st[4*q+0] = t4.f[0]; st[4*q+1] = t4.f[1]; st[4*q+2] = t4.f[2]; st[4*q+3] = t4.f[3];
                    }
                } else {
                    #pragma unroll
                    for (int q = 0; q < 16; ++q) st[q] = 0.f;
                }
                #pragma unroll
                for (int kr = 0; kr < 16; ++kr) {
                    const int k = p0 + kr;
                    float dk  = __shfl(st[kr], k, 64);
                    float rkv = 1.0f / dk;
                    if (lane == k) myrk = rkv;
                    float coef = st[kr] * rkv;
                    coef = (lane > k) ? coef : 0.f;
                    lw[kr] = coef;
                    #pragma unroll
                    for (int jr = kr + 1; jr < 16; ++jr) {
                        float wjk = __shfl(st[kr], p0 + jr, 64);
                        st[jr] -= coef * wjk;
                    }
                }
                if (lane >= p0) {
                    #pragma unroll
                    for (int q = 0; q < 4; ++q) {
                        float4 v; v.x = st[4*q+0]; v.y = st[4*q+1]; v.z = st[4*q+2]; v.w = st[4*q+3];
                        *(float4*)&Aug[lane * AUGW + p0 + 4 * q] = v;   // W (raw factored)
                    }
                    if (lane < p0 + 16) rk[lane] = myrk;
                }
                if (lane >= p0 + 16) {   // only trailing rows' L are ever read (by F3)
                    #pragma unroll
                    for (int q = 0; q < 4; ++q) {
                        float4 v; v.x = lw[4*q+0]; v.y = lw[4*q+1]; v.z = lw[4*q+2]; v.w = lw[4*q+3];
                        *(float4*)&LW(lane, 4 * q) = v;                 // true L factors
                    }
                }
                // F2: panel-row E/z triangular update (same wave, register col-slices)
                float ec[16], zr[16];
                #pragma unroll
                for (int r2 = 0; r2 < 16; ++r2) {
                    ec[r2] = Aug[(p0 + r2) * AUGW + 64 + lane];
                    zr[r2] = Aug[(p0 + r2) * AUGW + 128];
                }
                #pragma unroll
                for (int kp = 0; kp < 15; ++kp) {
                    #pragma unroll
                    for (int r2 = kp + 1; r2 < 16; ++r2) {
                        float L = __shfl(lw[kp], p0 + r2, 64);
                        ec[r2] -= L * ec[kp];
                        zr[r2] -= L * zr[kp];
                    }
                }
                #pragma unroll
                for (int r2 = 0; r2 < 16; ++r2)
                    Aug[(p0 + r2) * AUGW + 64 + lane] = ec[r2];
                if (lane == 0) {
                    #pragma unroll
                    for (int r2 = 0; r2 < 16; ++r2)
                        Aug[(p0 + r2) * AUGW + 128] = zr[r2];
                }
            }
            __syncthreads();

            // F3: rank-16 trailing update (empty for p==3 -> skipped, saves a barrier)
            if (p < 3) {
                const int TS  = (p == 0) ? 78 : (p == 1) ? 36 : 10;
                const int rows = 48 - 16 * p;                 // trailing rows
                const int TE  = (rows / 4) * 17;
                const int tot = TS + TE;
                const int ofs = 4 * (p + 1);
                #pragma unroll 1
                for (int t = tid; t < tot; t += 256) {
                    int i0, Cb; bool isS;
                    if (t < TS) {
                        int rr = (int)((sqrtf(8.0f * (float)t + 1.0f) - 1.0f) * 0.5f);
                        if ((rr + 1) * (rr + 2) / 2 <= t) ++rr;
                        if (rr * (rr + 1) / 2 > t) --rr;
                        int cc = t - rr * (rr + 1) / 2;
                        i0 = 4 * (ofs + rr); Cb = 4 * (ofs + cc); isS = true;
                    } else {
                        int e2 = t - TS;
                        i0 = 4 * (ofs + e2 / 17); Cb = 64 + 4 * (e2 % 17); isS = false;
                    }
                    F4 acc[4];
                    #pragma unroll
                    for (int dr = 0; dr < 4; ++dr) acc[dr].v = *(const float4*)&Aug[(i0 + dr) * AUGW + Cb];
                    #pragma unroll
                    for (int c4 = 0; c4 < 4; ++c4) {
                        F4 a4[4];
                        #pragma unroll
                        for (int dr = 0; dr < 4; ++dr) a4[dr].v = *(const float4*)&LW(i0 + dr, 4 * c4);
                        if (isS) {
                            F4 b4[4];
                            #pragma unroll
                            for (int dc = 0; dc < 4; ++dc) b4[dc].v = *(const float4*)&Aug[(Cb + dc) * AUGW + p0 + 4 * c4];
                            #pragma unroll
                            for (int dr = 0; dr < 4; ++dr)
                                #pragma unroll
                                for (int dc = 0; dc < 4; ++dc)
                                    #pragma unroll
                                    for (int dk = 0; dk < 4; ++dk)
                                        acc[dr].f[dc] -= a4[dr].f[dk] * b4[dc].f[dk];
                        } else {
                            F4 b4[4];
                            #pragma unroll
                            for (int dk = 0; dk < 4; ++dk) b4[dk].v = *(const float4*)&Aug[(p0 + 4 * c4 + dk) * AUGW + Cb];
                            #pragma unroll
                            for (int dk = 0; dk < 4; ++dk)
                                #pragma unroll
                                for (int dr = 0; dr < 4; ++dr)
                                    #pragma unroll
                                    for (int dc = 0; dc < 4; ++dc)
                                        acc[dr].f[dc] -= a4[dr].f[dk] * b4[dk].f[dc];
                        }
                    }
                    #pragma unroll
                    for (int dr = 0; dr < 4; ++dr) *(float4*)&Aug[(i0 + dr) * AUGW + Cb] = acc[dr].v;
                }
                __syncthreads();
            }
        }

        // ---- Phase G: P_post (lower + mirrored upper + out_ls from regs, tid<136);
        //      mu_post + out_mu (wave 3); stage next u/y (tid 136..159);
        //      convergence stats (all waves)
        const size_t o = (size_t)((s + 1) * NBS + b) * N;
        float tdmax = 0.f, tpmax = 0.f;
        if (tid < 136) {
            const int i0 = 4 * Rlow, j0 = 4 * Clow;
            F4 acc[4], oldv[4];
            #pragma unroll
            for (int dr = 0; dr < 4; ++dr) { acc[dr].v = *(const float4*)&P[(i0 + dr) * PW + j0]; oldv[dr].v = acc[dr].v; }
            #pragma unroll 2
            for (int c4 = 0; c4 < 16; ++c4) {
                F4 rv; rv.v = *(const float4*)&rk[4 * c4];
                F4 ea[4], eb[4];
                #pragma unroll
                for (int dk = 0; dk < 4; ++dk) ea[dk].v = *(const float4*)&Aug[(4 * c4 + dk) * AUGW + 64 + i0];
                #pragma unroll
                for (int dk = 0; dk < 4; ++dk) eb[dk].v = *(const float4*)&Aug[(4 * c4 + dk) * AUGW + 64 + j0];
                #pragma unroll
                for (int dk = 0; dk < 4; ++dk) {
                    float sc[4];
                    #pragma unroll
                    for (int dr = 0; dr < 4; ++dr) sc[dr] = ea[dk].f[dr] * rv.f[dk];
                    #pragma unroll
                    for (int dr = 0; dr < 4; ++dr)
                        #pragma unroll
                        for (int dc = 0; dc < 4; ++dc)
                            acc[dr].f[dc] -= sc[dr] * eb[dk].f[dc];
                }
            }
            #pragma unroll
            for (int dr = 0; dr < 4; ++dr) *(float4*)&P[(i0 + dr) * PW + j0] = acc[dr].v;
            // convergence stats: Delta = P_post_new - P_post_prev (prev diag had +Q)
            #pragma unroll
            for (int dr = 0; dr < 4; ++dr)
                #pragma unroll
                for (int dc = 0; dc < 4; ++dc) {
                    float d = acc[dr].f[dc] - oldv[dr].f[dc];
                    if (Rlow == Clow && dr == dc) d += Qd[i0 + dr];
                    tdmax = fmaxf(tdmax, fabsf(d));
                    tpmax = fmaxf(tpmax, fabsf(acc[dr].f[dc]));
                }
            if (Rlow != Clow) {
                // mirror to upper from registers (no extra phase, no re-read)
                #pragma unroll
                for (int dc = 0; dc < 4; ++dc) {
                    float4 v; v.x = acc[0].f[dc]; v.y = acc[1].f[dc]; v.z = acc[2].f[dc]; v.w = acc[3].f[dc];
                    *(float4*)&P[(j0 + dc) * PW + i0] = v;
                }
            } else {
                #pragma unroll
                for (int dr = 0; dr < 4; ++dr)
                    out_ls[o + i0 + dr] = 0.5f * logf(acc[dr].f[dr]);
            }
        }
        if (tid >= 192) {   // mu_post = mu_pred + E~^T (rk .* z~)   (wave 3)
            const int i = tid - 192;
            wv[i] = rk[i] * Aug[i * AUGW + 128];
            float acc = mup[i];
            #pragma unroll 4
            for (int c4 = 0; c4 < 16; ++c4) {
                F4 wq; wq.v = *(const float4*)&wv[4 * c4];
                #pragma unroll
                for (int dk = 0; dk < 4; ++dk)
                    acc += Aug[(4 * c4 + dk) * AUGW + 64 + i] * wq.f[dk];
            }
            mu[i] = acc;
            out_mu[o + i] = acc;
        }
        if (tid >= 136 && tid < 144) {          // stage u for s+1
            int q = tid - 136;
            *(float4*)&uvec[4 * q] = *(const float4*)&ext[(size_t)((s + 1) * NBS + b) * NI + 4 * q];
        }
        if (tid >= 144 && tid < 160 && s < L_SEQ - 2) {   // stage y for s+1 (obs row s+2)
            int q = tid - 144;
            *(float4*)&yv[4 * q] = *(const float4*)&obs[(size_t)((s + 2) * NBS + b) * N + 4 * q];
        }
        // block-wide max reduce of convergence stats (12 shfl + 2 atomics/wave)
        #pragma unroll
        for (int off = 32; off; off >>= 1) {
            tdmax = fmaxf(tdmax, __shfl_xor(tdmax, off, 64));
            tpmax = fmaxf(tpmax, __shfl_xor(tpmax, off, 64));
        }
        if ((tid & 63) == 0) {
            atomicMax(&flagI[0], __float_as_int(tdmax));
            atomicMax(&flagI[1], __float_as_int(tpmax));
        }
        __syncthreads();

        // uniform convergence decision (flags reset next step in phase E, after D-barrier)
        {
            float dm = __int_as_float(flagI[0]);
            float pm = __int_as_float(flagI[1]);
            bool conv = (s >= CONV_MINS) && (dm <= CONV_TAU * pm);
            streak = conv ? (streak + 1) : 0;
            if (streak >= 2) { sb = s + 1; break; }
        }
    }

    // ---------------- converged tail: frozen covariance ----------------
    if (sb > 0) {
        // One-time: Kg = P_post * H^T * R^{-1}  (information-filter gain identity),
        // stored in Aug's E panel (cols 64..127); lsc = frozen out_ls vector.
        {
            const int i0 = 4 * ty, j0 = 4 * tx;
            float acc[4][4];
            #pragma unroll
            for (int a = 0; a < 4; ++a)
                #pragma unroll
                for (int c = 0; c < 4; ++c) acc[a][c] = 0.f;
            #pragma unroll 4
            for (int c4 = 0; c4 < 16; ++c4) {
                F4 a4[4], b4[4];
                #pragma unroll
                for (int dr = 0; dr < 4; ++dr) a4[dr].v = *(const float4*)&P[(i0 + dr) * PW + 4 * c4];
                #pragma unroll
                for (int dc = 0; dc < 4; ++dc) b4[dc].v = *(const float4*)&Hs[(j0 + dc) * HW + 4 * c4];
                #pragma unroll
                for (int dr = 0; dr < 4; ++dr)
                    #pragma unroll
                    for (int dc = 0; dc < 4; ++dc)
                        #pragma unroll
                        for (int dk = 0; dk < 4; ++dk)
                            acc[dr][dc] += a4[dr].f[dk] * b4[dc].f[dk];
            }
            float ri[4];
            #pragma unroll
            for (int dc = 0; dc < 4; ++dc) ri[dc] = 1.0f / Rd[j0 + dc];
            #pragma unroll
            for (int dr = 0; dr < 4; ++dr) {
                float4 v; v.x = acc[dr][0]*ri[0]; v.y = acc[dr][1]*ri[1];
                          v.z = acc[dr][2]*ri[2]; v.w = acc[dr][3]*ri[3];
                *(float4*)&Aug[(i0 + dr) * AUGW + 64 + j0] = v;
            }
            if (tid < 64) lsc[tid] = 0.5f * logf(P[tid * PW + tid]);
        }
        __syncthreads();

        #pragma unroll 1
        for (int s2 = sb; s2 < L_SEQ - 1; ++s2) {
            const size_t o2 = (size_t)((s2 + 1) * NBS + b) * N;
            // ph1: mu_pred
            if (tid < 64) {
                float acc = mu[tid];
                #pragma unroll
                for (int k = 0; k < NI; ++k) acc += Bt[k * 64 + tid] * uvec[k];
                mup[tid] = acc;
            }
            __syncthreads();
            // ph2: z = y - H mu_pred ; out_ls (frozen) ; stage next u
            if (tid < 64) {
                float acc = yv[tid];
                #pragma unroll 4
                for (int c4 = 0; c4 < 16; ++c4) {
                    F4 h; h.v = *(const float4*)&Hs[tid * HW + 4 * c4];
                    F4 m; m.v = *(const float4*)&mup[4 * c4];
                    acc -= h.f[0]*m.f[0] + h.f[1]*m.f[1] + h.f[2]*m.f[2] + h.f[3]*m.f[3];
                }
                wv[tid] = acc;
                out_ls[o2 + tid] = lsc[tid];
            } else if (tid < 72) {
                int q = tid - 64;
                *(float4*)&uvec[4 * q] = *(const float4*)&ext[(size_t)((s2 + 1) * NBS + b) * NI + 4 * q];
            }
            __syncthreads();
            // ph3: mu_post = mu_pred + Kg z ; stage next y
            if (tid < 64) {
                float acc = mup[tid];
                #pragma unroll 4
                for (int c4 = 0; c4 < 16; ++c4) {
                    F4 kg; kg.v = *(const float4*)&Aug[tid * AUGW + 64 + 4 * c4];
                    F4 w;  w.v  = *(const float4*)&wv[4 * c4];
                    acc += kg.f[0]*w.f[0] + kg.f[1]*w.f[1] + kg.f[2]*w.f[2] + kg.f[3]*w.f[3];
                }
                mu[tid] = acc;
                out_mu[o2 + tid] = acc;
            } else if (tid < 80 && s2 < L_SEQ - 2) {
                int q = tid - 64;
                *(float4*)&yv[4 * q] = *(const float4*)&obs[(size_t)((s2 + 2) * NBS + b) * N + 4 * q];
            }
            __syncthreads();
        }
    }
}

extern "C" void kernel_launch(void* const* d_in, const int* in_sizes, int n_in,
                              void* d_out, int out_size, void* d_ws, size_t ws_size,
                              hipStream_t stream) {
    const float* ext = (const float*)d_in[0];
    const float* obs = (const float*)d_in[1];
    const float* mu0 = (const float*)d_in[2];
    const float* sg0 = (const float*)d_in[3];
    const float* lsg = (const float*)d_in[4];
    const float* Bm  = (const float*)d_in[5];
    const float* Hm  = (const float*)d_in[6];
    const float* ldl = (const float*)d_in[7];
    float* out_mu = (float*)d_out;
    float* out_ls = out_mu + (size_t)L_SEQ * NBS * N;

    size_t smem = (size_t)SM_FLOATS * sizeof(float);   // 78992 B
    hipFuncSetAttribute(reinterpret_cast<const void*>(akf5),
                        hipFuncAttributeMaxDynamicSharedMemorySize, (int)smem);

    akf5<<<dim3(NBS), dim3(256), smem, stream>>>(
        ext, obs, mu0, sg0, lsg, Bm, Hm, ldl, out_mu, out_ls);
}

// Round 5
// 13623.372 us; speedup vs baseline: 1.3225x; 1.0921x over previous
//
#include <hip/hip_runtime.h>
#include <math.h>

#define L_SEQ 500
#define NBS   512
#define N     64
#define NI    32
#define AUGW  132   // Aug row stride: cols 0..63 S(lower), 64..127 E, 128 z, 129..131 pad(0)
#define PW    68    // P row stride
#define HW    68    // H row stride

// LDS layout (floats); every array base and row stride is 16B aligned
#define OFF_AUG 0
#define OFF_P   (OFF_AUG + 64*AUGW)   //  8448
#define OFF_H   (OFF_P   + 64*PW)     // 12800
#define OFF_BT  (OFF_H   + 64*HW)     // 17152  (B transposed: Bt[k*64+i] = B[i][k])
#define OFF_RK  (OFF_BT  + NI*64)     // 19200
#define OFF_QD  (OFF_RK  + 64)
#define OFF_RD  (OFF_QD  + 64)
#define OFF_MU  (OFF_RD  + 64)
#define OFF_MUP (OFF_MU  + 64)
#define OFF_WV  (OFF_MUP + 64)
#define OFF_U   (OFF_WV  + 64)
#define OFF_YV  (OFF_U   + 32)        // prefetched observation row (64 floats)
#define OFF_LSC (OFF_YV  + 64)        // frozen out_ls vector (converged mode)
#define OFF_FLG (OFF_LSC + 64)        // [0]=dmax bits, [1]=pmax bits (int)
#define SM_FLOATS (OFF_FLG + 4)       // 19748 floats = 78992 B -> 2 blocks/CU

#define CONV_TAU  2e-5f
#define CONV_MINS 20

union F4 { float4 v; float f[4]; };

// Lw (true L factors) overlaid in Aug's strict upper triangle: row i (i in [16,64))
// lives at Aug[(i-16)*AUGW + 48 + k], k in [0,16).
#define LW(i,k) Aug[((i)-16)*AUGW + 48 + (k)]

// uniform-lane shuffle: v_readlane (VALU, ~8cyc) instead of ds_bpermute (~35cyc).
// All F1/F2 shuffle sources are wave-uniform lane indices.
__device__ __forceinline__ float rl(float x, int srclane) {
    return __int_as_float(__builtin_amdgcn_readlane(__float_as_int(x), srclane));
}

__global__ __launch_bounds__(256, 2)
void akf7(const float* __restrict__ ext,   // (500,512,32)
          const float* __restrict__ obs,   // (500,512,64)
          const float* __restrict__ mu0,   // (512,64)
          const float* __restrict__ sg0,   // (512,64)
          const float* __restrict__ lsg,   // (64)
          const float* __restrict__ Bm,    // (64,32)
          const float* __restrict__ Hm,    // (64,64)
          const float* __restrict__ ldl,   // (64)
          float* __restrict__ out_mu,      // (500,512,64)
          float* __restrict__ out_ls)      // (500,512,64)
{
    extern __shared__ float sm[];
    float* Aug = sm + OFF_AUG;
    float* P   = sm + OFF_P;
    float* Hs  = sm + OFF_H;
    float* Bt  = sm + OFF_BT;
    float* rk  = sm + OFF_RK;
    float* Qd  = sm + OFF_QD;
    float* Rd  = sm + OFF_RD;
    float* mu  = sm + OFF_MU;
    float* mup = sm + OFF_MUP;
    float* wv  = sm + OFF_WV;
    float* uvec= sm + OFF_U;
    float* yv  = sm + OFF_YV;
    float* lsc = sm + OFF_LSC;
    int*   flagI = (int*)(sm + OFF_FLG);

    const int b   = blockIdx.x;
    const int tid = threadIdx.x;
    const int tx  = tid & 15;
    const int ty  = tid >> 4;

    // packed lower-incl-diag 16x16 tile map for tid<136 (phase E)
    int Rlow = 0, Clow = 0;
    {
        int t = tid < 136 ? tid : 0;
        int R = (int)((sqrtf(8.0f * (float)t + 1.0f) - 1.0f) * 0.5f);
        if ((R + 1) * (R + 2) / 2 <= t) ++R;
        if (R * (R + 1) / 2 > t) --R;
        Rlow = R; Clow = t - R * (R + 1) / 2;
    }
    // same map for tid-64 (incremental phase-G tiles, threads 64..199)
    int Rg = 0, Cg = 0;
    {
        int t = (tid >= 64 && tid < 200) ? (tid - 64) : 0;
        int R = (int)((sqrtf(8.0f * (float)t + 1.0f) - 1.0f) * 0.5f);
        if ((R + 1) * (R + 2) / 2 <= t) ++R;
        if (R * (R + 1) / 2 > t) --R;
        Rg = R; Cg = t - R * (R + 1) / 2;
    }

    // ---------------- init ----------------
    if (tid < 64) {
        int i = tid;
        float q = expf(lsg[i]); Qd[i] = q * q;
        float r = expf(ldl[i]); Rd[i] = r * r;
        float m0 = mu0[b * N + i];
        float s0 = sg0[b * N + i];
        mu[i]  = m0;
        mup[i] = s0;                       // temp: sigma0
        out_mu[(size_t)b * N + i] = m0;
        out_ls[(size_t)b * N + i] = logf(s0);
        Aug[i * AUGW + 129] = 0.f; Aug[i * AUGW + 130] = 0.f; Aug[i * AUGW + 131] = 0.f;
    }
    if (tid == 0) { flagI[0] = 0; flagI[1] = 0; }
    for (int e = tid; e < N * N; e += 256) {
        Hs[(e >> 6) * HW + (e & 63)] = Hm[e];
    }
    for (int e = tid; e < N * NI; e += 256) {
        int i = e >> 5, k = e & 31;
        Bt[k * 64 + i] = Bm[e];
    }
    __syncthreads();
    for (int e = tid; e < N * N; e += 256) {
        int i = e >> 6, j = e & 63;
        float v = 0.f;
        if (i == j) { float s = mup[i]; v = s * s; }
        P[i * PW + j] = v;
    }
    if (tid >= 192 && tid < 200) {     // stage u for s=0
        int q = tid - 192;
        *(float4*)&uvec[4 * q] = *(const float4*)&ext[(size_t)b * NI + 4 * q];
    }
    if (tid >= 200 && tid < 216) {     // stage y for s=0 (obs row 1)
        int q = tid - 200;
        *(float4*)&yv[4 * q] = *(const float4*)&obs[(size_t)(NBS + b) * N + 4 * q];
    }
    __syncthreads();

    int streak = 0, sb = 0;

    // ---------------- full time loop (until covariance converges) ----------------
    #pragma unroll 1
    for (int s = 0; s < L_SEQ - 1; ++s) {
        // ---- Phase D: E = H * (P + Q) on all 256 threads.
        //      Wave-0 prologue (wave-synchronous): mu_pred, innov.
        if (tid < 64) {
            float acc = mu[tid];
            #pragma unroll
            for (int k = 0; k < NI; ++k) acc += Bt[k * 64 + tid] * uvec[k];
            mup[tid] = acc;
        }
        __builtin_amdgcn_wave_barrier();
        if (tid < 64) {
            float acc = yv[tid];                          // prefetched obs(s+1)
            #pragma unroll 4
            for (int c4 = 0; c4 < 16; ++c4) {
                F4 h; h.v = *(const float4*)&Hs[tid * HW + 4 * c4];
                F4 m; m.v = *(const float4*)&mup[4 * c4];
                acc -= h.f[0]*m.f[0] + h.f[1]*m.f[1] + h.f[2]*m.f[2] + h.f[3]*m.f[3];
            }
            Aug[tid * AUGW + 128] = acc;
        }
        {
            const int i0 = 4 * ty, j0 = 4 * tx;
            float acc[4][4];
            // Q folded into E: E = H*P + H*diag(Q); P diag itself updated in phase E
            F4 qv; qv.v = *(const float4*)&Qd[j0];
            #pragma unroll
            for (int dr = 0; dr < 4; ++dr) {
                F4 hv; hv.v = *(const float4*)&Hs[(i0 + dr) * HW + j0];
                #pragma unroll
                for (int dc = 0; dc < 4; ++dc) acc[dr][dc] = hv.f[dc] * qv.f[dc];
            }
            #pragma unroll 4
            for (int c4 = 0; c4 < 16; ++c4) {
                F4 h4[4], p4[4];
                #pragma unroll
                for (int dr = 0; dr < 4; ++dr) h4[dr].v = *(const float4*)&Hs[(i0 + dr) * HW + 4 * c4];
                #pragma unroll
                for (int dk = 0; dk < 4; ++dk) p4[dk].v = *(const float4*)&P[(4 * c4 + dk) * PW + j0];
                #pragma unroll
                for (int dk = 0; dk < 4; ++dk)
                    #pragma unroll
                    for (int dr = 0; dr < 4; ++dr)
                        #pragma unroll
                        for (int dc = 0; dc < 4; ++dc)
                            acc[dr][dc] += h4[dr].f[dk] * p4[dk].f[dc];
            }
            #pragma unroll
            for (int dr = 0; dr < 4; ++dr) {
                float4 v; v.x = acc[dr][0]; v.y = acc[dr][1]; v.z = acc[dr][2]; v.w = acc[dr][3];
                *(float4*)&Aug[(i0 + dr) * AUGW + 64 + j0] = v;
            }
        }
        __syncthreads();

        // ---- Phase E: S lower = E * H^T + R (tid<136); P diag += Q (tid 136..199);
        //      reset convergence flags (tid 200)
        if (tid < 136) {
            const int i0 = 4 * Rlow, j0 = 4 * Clow;
            float acc[4][4];
            #pragma unroll
            for (int a = 0; a < 4; ++a)
                #pragma unroll
                for (int c = 0; c < 4; ++c) acc[a][c] = 0.f;
            #pragma unroll 4
            for (int c4 = 0; c4 < 16; ++c4) {
                F4 a4[4], b4[4];
                #pragma unroll
                for (int dr = 0; dr < 4; ++dr) a4[dr].v = *(const float4*)&Aug[(i0 + dr) * AUGW + 64 + 4 * c4];
                #pragma unroll
                for (int dc = 0; dc < 4; ++dc) b4[dc].v = *(const float4*)&Hs[(j0 + dc) * HW + 4 * c4];
                #pragma unroll
                for (int dr = 0; dr < 4; ++dr)
                    #pragma unroll
                    for (int dc = 0; dc < 4; ++dc)
                        #pragma unroll
                        for (int dk = 0; dk < 4; ++dk)
                            acc[dr][dc] += a4[dr].f[dk] * b4[dc].f[dk];
            }
            #pragma unroll
            for (int dr = 0; dr < 4; ++dr) {
                #pragma unroll
                for (int dc = 0; dc < 4; ++dc)
                    if (i0 + dr == j0 + dc) acc[dr][dc] += Rd[i0 + dr];
                float4 v; v.x = acc[dr][0]; v.y = acc[dr][1]; v.z = acc[dr][2]; v.w = acc[dr][3];
                *(float4*)&Aug[(i0 + dr) * AUGW + j0] = v;
            }
        } else if (tid < 200) {
            const int i = tid - 136;
            P[i * PW + i] += Qd[i];        // P becomes P_pred; read by phase G
        } else if (tid == 200) {
            flagI[0] = 0; flagI[1] = 0;    // reset for this step's final-phase atomics
        }
        __syncthreads();

        // ---- Panels: F1/F2 on wave 0 (readlane chains), incremental-G on tids 64..199,
        //      F3 trailing update on all threads.  G chunk cp uses Etilde/rk of panel cp,
        //      final right after slot cp -> computed in slot cp+1, overlapped with F1F2.
        F4 gacc[4];
        #pragma unroll 1
        for (int p = 0; p < 4; ++p) {
            const int p0 = 16 * p;
            if (tid < 64) {
                // F1: panel factor (wave 0, wave-synchronous, registers + readlane)
                const int lane = tid;
                float st[16], lw[16], myrk = 0.f;
                if (lane >= p0) {
                    #pragma unroll
                    for (int q = 0; q < 4; ++q) {
                        F4 t4; t4.v = *(const float4*)&Aug[lane * AUGW + p0 + 4 * q];
                        st[4*q+0] = t4.f[0]; st[4*q+1] = t4.f[1]; st[4*q+2] = t4.f[2]; st[4*q+3] = t4.f[3];
                    }
                } else {
                    #pragma unroll
                    for (int q = 0; q < 16; ++q) st[q] = 0.f;
                }
                #pragma unroll
                for (int kr = 0; kr < 16; ++kr) {
                    const int k = p0 + kr;
                    float dk  = rl(st[kr], k);
                    float rkv = __builtin_amdgcn_rcpf(dk);   // ~1ulp; Riccati self-corrects
                    if (lane == k) myrk = rkv;
                    float coef = st[kr] * rkv;
                    coef = (lane > k) ? coef : 0.f;
                    lw[kr] = coef;
                    #pragma unroll
                    for (int jr = kr + 1; jr < 16; ++jr) {
                        float wjk = rl(st[kr], p0 + jr);
                        st[jr] -= coef * wjk;
                    }
                }
                if (lane >= p0) {
                    #pragma unroll
                    for (int q = 0; q < 4; ++q) {
                        float4 v; v.x = st[4*q+0]; v.y = st[4*q+1]; v.z = st[4*q+2]; v.w = st[4*q+3];
                        *(float4*)&Aug[lane * AUGW + p0 + 4 * q] = v;   // W (raw factored)
                    }
                    if (lane < p0 + 16) rk[lane] = myrk;
                }
                if (lane >= p0 + 16) {   // only trailing rows' L are ever read (by F3)
                    #pragma unroll
                    for (int q = 0; q < 4; ++q) {
                        float4 v; v.x = lw[4*q+0]; v.y = lw[4*q+1]; v.z = lw[4*q+2]; v.w = lw[4*q+3];
                        *(float4*)&LW(lane, 4 * q) = v;                 // true L factors
                    }
                }
                // F2: panel-row E/z triangular update (same wave, readlane)
                float ec[16], zr[16];
                #pragma unroll
                for (int r2 = 0; r2 < 16; ++r2) {
                    ec[r2] = Aug[(p0 + r2) * AUGW + 64 + lane];
                    zr[r2] = Aug[(p0 + r2) * AUGW + 128];
                }
                #pragma unroll
                for (int kp = 0; kp < 15; ++kp) {
                    #pragma unroll
                    for (int r2 = kp + 1; r2 < 16; ++r2) {
                        float L = rl(lw[kp], p0 + r2);
                        ec[r2] -= L * ec[kp];
                        zr[r2] -= L * zr[kp];
                    }
                }
                #pragma unroll
                for (int r2 = 0; r2 < 16; ++r2)
                    Aug[(p0 + r2) * AUGW + 64 + lane] = ec[r2];
                if (lane == 0) {
                    #pragma unroll
                    for (int r2 = 0; r2 < 16; ++r2)
                        Aug[(p0 + r2) * AUGW + 128] = zr[r2];
                }
            } else if (p > 0 && tid < 200) {
                // incremental G: chunk cp = p-1 (panel p-1's Etilde rows + rk are final)
                const int cp = p - 1;
                const int i0 = 4 * Rg, j0 = 4 * Cg;
                if (p == 1) {
                    #pragma unroll
                    for (int dr = 0; dr < 4; ++dr) gacc[dr].v = *(const float4*)&P[(i0 + dr) * PW + j0];
                }
                #pragma unroll
                for (int q = 0; q < 4; ++q) {
                    const int c4 = 4 * cp + q;
                    F4 rv; rv.v = *(const float4*)&rk[4 * c4];
                    F4 ea[4], eb[4];
                    #pragma unroll
                    for (int dk = 0; dk < 4; ++dk) ea[dk].v = *(const float4*)&Aug[(4 * c4 + dk) * AUGW + 64 + i0];
                    #pragma unroll
                    for (int dk = 0; dk < 4; ++dk) eb[dk].v = *(const float4*)&Aug[(4 * c4 + dk) * AUGW + 64 + j0];
                    #pragma unroll
                    for (int dk = 0; dk < 4; ++dk) {
                        float sc[4];
                        #pragma unroll
                        for (int dr = 0; dr < 4; ++dr) sc[dr] = ea[dk].f[dr] * rv.f[dk];
                        #pragma unroll
                        for (int dr = 0; dr < 4; ++dr)
                            #pragma unroll
                            for (int dc = 0; dc < 4; ++dc)
                                gacc[dr].f[dc] -= sc[dr] * eb[dk].f[dc];
                    }
                }
            }
            __syncthreads();

            // F3: rank-16 trailing update (empty for p==3)
            if (p < 3) {
                const int TS  = (p == 0) ? 78 : (p == 1) ? 36 : 10;
                const int rows = 48 - 16 * p;                 // trailing rows
                const int TE  = (rows / 4) * 17;
                const int tot = TS + TE;
                const int ofs = 4 * (p + 1);
                #pragma unroll 1
                for (int t = tid; t < tot; t += 256) {
                    int i0, Cb; bool isS;
                    if (t < TS) {
                        int rr = (int)((sqrtf(8.0f * (float)t + 1.0f) - 1.0f) * 0.5f);
                        if ((rr + 1) * (rr + 2) / 2 <= t) ++rr;
                        if (rr * (rr + 1) / 2 > t) --rr;
                        int cc = t - rr * (rr + 1) / 2;
                        i0 = 4 * (ofs + rr); Cb = 4 * (ofs + cc); isS = true;
                    } else {
                        int e2 = t - TS;
                        i0 = 4 * (ofs + e2 / 17); Cb = 64 + 4 * (e2 % 17); isS = false;
                    }
                    F4 acc[4];
                    #pragma unroll
                    for (int dr = 0; dr < 4; ++dr) acc[dr].v = *(const float4*)&Aug[(i0 + dr) * AUGW + Cb];
                    #pragma unroll
                    for (int c4 = 0; c4 < 4; ++c4) {
                        F4 a4[4];
                        #pragma unroll
                        for (int dr = 0; dr < 4; ++dr) a4[dr].v = *(const float4*)&LW(i0 + dr, 4 * c4);
                        if (isS) {
                            F4 b4[4];
                            #pragma unroll
                            for (int dc = 0; dc < 4; ++dc) b4[dc].v = *(const float4*)&Aug[(Cb + dc) * AUGW + p0 + 4 * c4];
                            #pragma unroll
                            for (int dr = 0; dr < 4; ++dr)
                                #pragma unroll
                                for (int dc = 0; dc < 4; ++dc)
                                    #pragma unroll
                                    for (int dk = 0; dk < 4; ++dk)
                                        acc[dr].f[dc] -= a4[dr].f[dk] * b4[dc].f[dk];
                        } else {
                            F4 b4[4];
                            #pragma unroll
                            for (int dk = 0; dk < 4; ++dk) b4[dk].v = *(const float4*)&Aug[(p0 + 4 * c4 + dk) * AUGW + Cb];
                            #pragma unroll
                            for (int dk = 0; dk < 4; ++dk)
                                #pragma unroll
                                for (int dr = 0; dr < 4; ++dr)
                                    #pragma unroll
                                    for (int dc = 0; dc < 4; ++dc)
                                        acc[dr].f[dc] -= a4[dr].f[dk] * b4[dk].f[dc];
                        }
                    }
                    #pragma unroll
                    for (int dr = 0; dr < 4; ++dr) *(float4*)&Aug[(i0 + dr) * AUGW + Cb] = acc[dr].v;
                }
                __syncthreads();
            }
        }

        // ---- Final phase: G-finish chunk 3 + P stores + out_ls + stats (tid 64..199);
        //      mu_post + out_mu (wave 0); stage next u/y (tid 200..223)
        const size_t o = (size_t)((s + 1) * NBS + b) * N;
        float tdmax = 0.f, tpmax = 0.f;
        if (tid >= 64 && tid < 200) {
            const int i0 = 4 * Rg, j0 = 4 * Cg;
            #pragma unroll
            for (int q = 0; q < 4; ++q) {
                const int c4 = 12 + q;
                F4 rv; rv.v = *(const float4*)&rk[4 * c4];
                F4 ea[4], eb[4];
                #pragma unroll
                for (int dk = 0; dk < 4; ++dk) ea[dk].v = *(const float4*)&Aug[(4 * c4 + dk) * AUGW + 64 + i0];
                #pragma unroll
                for (int dk = 0; dk < 4; ++dk) eb[dk].v = *(const float4*)&Aug[(4 * c4 + dk) * AUGW + 64 + j0];
                #pragma unroll
                for (int dk = 0; dk < 4; ++dk) {
                    float sc[4];
                    #pragma unroll
                    for (int dr = 0; dr < 4; ++dr) sc[dr] = ea[dk].f[dr] * rv.f[dk];
                    #pragma unroll
                    for (int dr = 0; dr < 4; ++dr)
                        #pragma unroll
                        for (int dc = 0; dc < 4; ++dc)
                            gacc[dr].f[dc] -= sc[dr] * eb[dk].f[dc];
                }
            }
            // stats vs P_pred (still in LDS, unmodified), then write
            #pragma unroll
            for (int dr = 0; dr < 4; ++dr) {
                F4 oldv; oldv.v = *(const float4*)&P[(i0 + dr) * PW + j0];
                #pragma unroll
                for (int dc = 0; dc < 4; ++dc) {
                    float d = gacc[dr].f[dc] - oldv.f[dc];
                    if (Rg == Cg && dr == dc) d += Qd[i0 + dr];
                    tdmax = fmaxf(tdmax, fabsf(d));
                    tpmax = fmaxf(tpmax, fabsf(gacc[dr].f[dc]));
                }
            }
            #pragma unroll
            for (int dr = 0; dr < 4; ++dr) *(float4*)&P[(i0 + dr) * PW + j0] = gacc[dr].v;
            if (Rg != Cg) {
                #pragma unroll
                for (int dc = 0; dc < 4; ++dc) {
                    float4 v; v.x = gacc[0].f[dc]; v.y = gacc[1].f[dc]; v.z = gacc[2].f[dc]; v.w = gacc[3].f[dc];
                    *(float4*)&P[(j0 + dc) * PW + i0] = v;
                }
            } else {
                #pragma unroll
                for (int dr = 0; dr < 4; ++dr)
                    out_ls[o + i0 + dr] = 0.5f * logf(gacc[dr].f[dr]);
            }
        } else if (tid < 64) {   // mu_post = mu_pred + E~^T (rk .* z~)  (wave 0)
            const int i = tid;
            wv[i] = rk[i] * Aug[i * AUGW + 128];
            float acc = mup[i];
            #pragma unroll 4
            for (int c4 = 0; c4 < 16; ++c4) {
                F4 wq; wq.v = *(const float4*)&wv[4 * c4];
                #pragma unroll
                for (int dk = 0; dk < 4; ++dk)
                    acc += Aug[(4 * c4 + dk) * AUGW + 64 + i] * wq.f[dk];
            }
            mu[i] = acc;
            out_mu[o + i] = acc;
        }
        if (tid >= 200 && tid < 208) {          // stage u for s+1
            int q = tid - 200;
            *(float4*)&uvec[4 * q] = *(const float4*)&ext[(size_t)((s + 1) * NBS + b) * NI + 4 * q];
        }
        if (tid >= 208 && tid < 224 && s < L_SEQ - 2) {   // stage y for s+1 (obs row s+2)
            int q = tid - 208;
            *(float4*)&yv[4 * q] = *(const float4*)&obs[(size_t)((s + 2) * NBS + b) * N + 4 * q];
        }
        // block-wide max reduce of convergence stats (12 shfl + 2 atomics/wave)
        #pragma unroll
        for (int off = 32; off; off >>= 1) {
            tdmax = fmaxf(tdmax, __shfl_xor(tdmax, off, 64));
            tpmax = fmaxf(tpmax, __shfl_xor(tpmax, off, 64));
        }
        if ((tid & 63) == 0) {
            atomicMax(&flagI[0], __float_as_int(tdmax));
            atomicMax(&flagI[1], __float_as_int(tpmax));
        }
        __syncthreads();

        // uniform convergence decision (flags reset next step in phase E, after D-barrier)
        {
            float dm = __int_as_float(flagI[0]);
            float pm = __int_as_float(flagI[1]);
            bool conv = (s >= CONV_MINS) && (dm <= CONV_TAU * pm);
            streak = conv ? (streak + 1) : 0;
            if (streak >= 2) { sb = s + 1; break; }
        }
    }

    // ---------------- converged tail: frozen covariance ----------------
    if (sb > 0) {
        // One-time: Kg = P_post * H^T * R^{-1}  (information-filter gain identity),
        // stored in Aug's E panel (cols 64..127); lsc = frozen out_ls vector.
        {
            const int i0 = 4 * ty, j0 = 4 * tx;
            float acc[4][4];
            #pragma unroll
            for (int a = 0; a < 4; ++a)
                #pragma unroll
                for (int c = 0; c < 4; ++c) acc[a][c] = 0.f;
            #pragma unroll 4
            for (int c4 = 0; c4 < 16; ++c4) {
                F4 a4[4], b4[4];
                #pragma unroll
                for (int dr = 0; dr < 4; ++dr) a4[dr].v = *(const float4*)&P[(i0 + dr) * PW + 4 * c4];
                #pragma unroll
                for (int dc = 0; dc < 4; ++dc) b4[dc].v = *(const float4*)&Hs[(j0 + dc) * HW + 4 * c4];
                #pragma unroll
                for (int dr = 0; dr < 4; ++dr)
                    #pragma unroll
                    for (int dc = 0; dc < 4; ++dc)
                        #pragma unroll
                        for (int dk = 0; dk < 4; ++dk)
                            acc[dr][dc] += a4[dr].f[dk] * b4[dc].f[dk];
            }
            float ri[4];
            #pragma unroll
            for (int dc = 0; dc < 4; ++dc) ri[dc] = 1.0f / Rd[j0 + dc];
            #pragma unroll
            for (int dr = 0; dr < 4; ++dr) {
                float4 v; v.x = acc[dr][0]*ri[0]; v.y = acc[dr][1]*ri[1];
                          v.z = acc[dr][2]*ri[2]; v.w = acc[dr][3]*ri[3];
                *(float4*)&Aug[(i0 + dr) * AUGW + 64 + j0] = v;
            }
            if (tid < 64) lsc[tid] = 0.5f * logf(P[tid * PW + tid]);
        }
        __syncthreads();

        #pragma unroll 1
        for (int s2 = sb; s2 < L_SEQ - 1; ++s2) {
            const size_t o2 = (size_t)((s2 + 1) * NBS + b) * N;
            // ph1: mu_pred
            if (tid < 64) {
                float acc = mu[tid];
                #pragma unroll
                for (int k = 0; k < NI; ++k) acc += Bt[k * 64 + tid] * uvec[k];
                mup[tid] = acc;
            }
            __syncthreads();
            // ph2: z = y - H mu_pred ; out_ls (frozen) ; stage next u
            if (tid < 64) {
                float acc = yv[tid];
                #pragma unroll 4
                for (int c4 = 0; c4 < 16; ++c4) {
                    F4 h; h.v = *(const float4*)&Hs[tid * HW + 4 * c4];
                    F4 m; m.v = *(const float4*)&mup[4 * c4];
                    acc -= h.f[0]*m.f[0] + h.f[1]*m.f[1] + h.f[2]*m.f[2] + h.f[3]*m.f[3];
                }
                wv[tid] = acc;
                out_ls[o2 + tid] = lsc[tid];
            } else if (tid < 72) {
                int q = tid - 64;
                *(float4*)&uvec[4 * q] = *(const float4*)&ext[(size_t)((s2 + 1) * NBS + b) * NI + 4 * q];
            }
            __syncthreads();
            // ph3: mu_post = mu_pred + Kg z ; stage next y
            if (tid < 64) {
                float acc = mup[tid];
                #pragma unroll 4
                for (int c4 = 0; c4 < 16; ++c4) {
                    F4 kg; kg.v = *(const float4*)&Aug[tid * AUGW + 64 + 4 * c4];
                    F4 w;  w.v  = *(const float4*)&wv[4 * c4];
                    acc += kg.f[0]*w.f[0] + kg.f[1]*w.f[1] + kg.f[2]*w.f[2] + kg.f[3]*w.f[3];
                }
                mu[tid] = acc;
                out_mu[o2 + tid] = acc;
            } else if (tid < 80 && s2 < L_SEQ - 2) {
                int q = tid - 64;
                *(float4*)&yv[4 * q] = *(const float4*)&obs[(size_t)((s2 + 2) * NBS + b) * N + 4 * q];
            }
            __syncthreads();
        }
    }
}

extern "C" void kernel_launch(void* const* d_in, const int* in_sizes, int n_in,
                              void* d_out, int out_size, void* d_ws, size_t ws_size,
                              hipStream_t stream) {
    const float* ext = (const float*)d_in[0];
    const float* obs = (const float*)d_in[1];
    const float* mu0 = (const float*)d_in[2];
    const float* sg0 = (const float*)d_in[3];
    const float* lsg = (const float*)d_in[4];
    const float* Bm  = (const float*)d_in[5];
    const float* Hm  = (const float*)d_in[6];
    const float* ldl = (const float*)d_in[7];
    float* out_mu = (float*)d_out;
    float* out_ls = out_mu + (size_t)L_SEQ * NBS * N;

    size_t smem = (size_t)SM_FLOATS * sizeof(float);   // 78992 B
    hipFuncSetAttribute(reinterpret_cast<const void*>(akf7),
                        hipFuncAttributeMaxDynamicSharedMemorySize, (int)smem);

    akf7<<<dim3(NBS), dim3(256), smem, stream>>>(
        ext, obs, mu0, sg0, lsg, Bm, Hm, ldl, out_mu, out_ls);
}

// Round 6
// 13579.926 us; speedup vs baseline: 1.3267x; 1.0032x over previous
//
#include <hip/hip_runtime.h>
#include <math.h>

#define L_SEQ 500
#define NBS   512
#define N     64
#define NI    32
#define AUGW  132   // Aug row stride: cols 0..63 S(lower), 64..127 E, 128 z, 129..131 pad(0)
#define PW    68    // P row stride
#define HW    68    // H row stride

// LDS layout (floats); every array base and row stride is 16B aligned
#define OFF_AUG 0
#define OFF_P   (OFF_AUG + 64*AUGW)   //  8448
#define OFF_H   (OFF_P   + 64*PW)     // 12800
#define OFF_BT  (OFF_H   + 64*HW)     // 17152  (B transposed: Bt[k*64+i] = B[i][k])
#define OFF_RK  (OFF_BT  + NI*64)     // 19200
#define OFF_QD  (OFF_RK  + 64)
#define OFF_RD  (OFF_QD  + 64)
#define OFF_MU  (OFF_RD  + 64)
#define OFF_MUP (OFF_MU  + 64)
#define OFF_WV  (OFF_MUP + 64)
#define OFF_U   (OFF_WV  + 64)
#define OFF_YV  (OFF_U   + 32)        // prefetched observation row (64 floats)
#define OFF_LSC (OFF_YV  + 64)        // frozen out_ls vector (converged mode)
#define OFF_FLG (OFF_LSC + 64)        // [0]=dmax bits, [1]=pmax bits (int)
#define SM_FLOATS (OFF_FLG + 4)       // 19748 floats = 78992 B -> 2 blocks/CU

#define CONV_TAU  2e-5f
#define CONV_MINS 20

union F4 { float4 v; float f[4]; };

// Lw (true L factors) overlaid in Aug's strict upper triangle: row i (i in [16,64))
// lives at Aug[(i-16)*AUGW + 48 + k], k in [0,16).
#define LW(i,k) Aug[((i)-16)*AUGW + 48 + (k)]

// uniform-lane shuffle: v_readlane (VALU) instead of ds_bpermute.
__device__ __forceinline__ float rl(float x, int srclane) {
    return __int_as_float(__builtin_amdgcn_readlane(__float_as_int(x), srclane));
}

__global__ __launch_bounds__(256, 2)
void akf8(const float* __restrict__ ext,   // (500,512,32)
          const float* __restrict__ obs,   // (500,512,64)
          const float* __restrict__ mu0,   // (512,64)
          const float* __restrict__ sg0,   // (512,64)
          const float* __restrict__ lsg,   // (64)
          const float* __restrict__ Bm,    // (64,32)
          const float* __restrict__ Hm,    // (64,64)
          const float* __restrict__ ldl,   // (64)
          float* __restrict__ out_mu,      // (500,512,64)
          float* __restrict__ out_ls)      // (500,512,64)
{
    extern __shared__ float sm[];
    float* Aug = sm + OFF_AUG;
    float* P   = sm + OFF_P;
    float* Hs  = sm + OFF_H;
    float* Bt  = sm + OFF_BT;
    float* rk  = sm + OFF_RK;
    float* Qd  = sm + OFF_QD;
    float* Rd  = sm + OFF_RD;
    float* mu  = sm + OFF_MU;
    float* mup = sm + OFF_MUP;
    float* wv  = sm + OFF_WV;
    float* uvec= sm + OFF_U;
    float* yv  = sm + OFF_YV;
    float* lsc = sm + OFF_LSC;
    int*   flagI = (int*)(sm + OFF_FLG);

    const int b   = blockIdx.x;
    const int tid = threadIdx.x;
    const int tx  = tid & 15;
    const int ty  = tid >> 4;

    // packed lower-incl-diag 16x16 tile map for tid<136 (phase E)
    int Rlow = 0, Clow = 0;
    {
        int t = tid < 136 ? tid : 0;
        int R = (int)((sqrtf(8.0f * (float)t + 1.0f) - 1.0f) * 0.5f);
        if ((R + 1) * (R + 2) / 2 <= t) ++R;
        if (R * (R + 1) / 2 > t) --R;
        Rlow = R; Clow = t - R * (R + 1) / 2;
    }
    // same map for tid-64 (incremental phase-G tiles, threads 64..199)
    int Rg = 0, Cg = 0;
    {
        int t = (tid >= 64 && tid < 200) ? (tid - 64) : 0;
        int R = (int)((sqrtf(8.0f * (float)t + 1.0f) - 1.0f) * 0.5f);
        if ((R + 1) * (R + 2) / 2 <= t) ++R;
        if (R * (R + 1) / 2 > t) --R;
        Rg = R; Cg = t - R * (R + 1) / 2;
    }

    // ---------------- init ----------------
    if (tid < 64) {
        int i = tid;
        float q = expf(lsg[i]); Qd[i] = q * q;
        float r = expf(ldl[i]); Rd[i] = r * r;
        float m0 = mu0[b * N + i];
        float s0 = sg0[b * N + i];
        mu[i]  = m0;
        mup[i] = s0;                       // temp: sigma0
        out_mu[(size_t)b * N + i] = m0;
        out_ls[(size_t)b * N + i] = logf(s0);
        Aug[i * AUGW + 129] = 0.f; Aug[i * AUGW + 130] = 0.f; Aug[i * AUGW + 131] = 0.f;
    }
    if (tid == 0) { flagI[0] = 0; flagI[1] = 0; }
    for (int e = tid; e < N * N; e += 256) {
        Hs[(e >> 6) * HW + (e & 63)] = Hm[e];
    }
    for (int e = tid; e < N * NI; e += 256) {
        int i = e >> 5, k = e & 31;
        Bt[k * 64 + i] = Bm[e];
    }
    __syncthreads();
    for (int e = tid; e < N * N; e += 256) {
        int i = e >> 6, j = e & 63;
        float v = 0.f;
        if (i == j) { float s = mup[i]; v = s * s; }
        P[i * PW + j] = v;
    }
    if (tid >= 192 && tid < 200) {     // stage u for s=0
        int q = tid - 192;
        *(float4*)&uvec[4 * q] = *(const float4*)&ext[(size_t)b * NI + 4 * q];
    }
    if (tid >= 200 && tid < 216) {     // stage y for s=0 (obs row 1)
        int q = tid - 200;
        *(float4*)&yv[4 * q] = *(const float4*)&obs[(size_t)(NBS + b) * N + 4 * q];
    }
    __syncthreads();

    int streak = 0, sb = 0;

    // ---------------- full time loop (until covariance converges) ----------------
    #pragma unroll 1
    for (int s = 0; s < L_SEQ - 1; ++s) {
        // ---- Phase D: E = H * (P + Q) on all 256 threads.
        //      Wave-0 prologue (wave-synchronous): mu_pred, innov.
        if (tid < 64) {
            float acc = mu[tid];
            #pragma unroll
            for (int k = 0; k < NI; ++k) acc += Bt[k * 64 + tid] * uvec[k];
            mup[tid] = acc;
        }
        __builtin_amdgcn_wave_barrier();
        if (tid < 64) {
            float acc = yv[tid];                          // prefetched obs(s+1)
            #pragma unroll 8
            for (int c4 = 0; c4 < 16; ++c4) {
                F4 h; h.v = *(const float4*)&Hs[tid * HW + 4 * c4];
                F4 m; m.v = *(const float4*)&mup[4 * c4];
                acc -= h.f[0]*m.f[0] + h.f[1]*m.f[1] + h.f[2]*m.f[2] + h.f[3]*m.f[3];
            }
            Aug[tid * AUGW + 128] = acc;
        }
        {
            const int i0 = 4 * ty, j0 = 4 * tx;
            float acc[4][4];
            // Q folded into E: E = H*P + H*diag(Q); P diag itself updated in phase E
            F4 qv; qv.v = *(const float4*)&Qd[j0];
            #pragma unroll
            for (int dr = 0; dr < 4; ++dr) {
                F4 hv; hv.v = *(const float4*)&Hs[(i0 + dr) * HW + j0];
                #pragma unroll
                for (int dc = 0; dc < 4; ++dc) acc[dr][dc] = hv.f[dc] * qv.f[dc];
            }
            #pragma unroll 8
            for (int c4 = 0; c4 < 16; ++c4) {
                F4 h4[4], p4[4];
                #pragma unroll
                for (int dr = 0; dr < 4; ++dr) h4[dr].v = *(const float4*)&Hs[(i0 + dr) * HW + 4 * c4];
                #pragma unroll
                for (int dk = 0; dk < 4; ++dk) p4[dk].v = *(const float4*)&P[(4 * c4 + dk) * PW + j0];
                #pragma unroll
                for (int dk = 0; dk < 4; ++dk)
                    #pragma unroll
                    for (int dr = 0; dr < 4; ++dr)
                        #pragma unroll
                        for (int dc = 0; dc < 4; ++dc)
                            acc[dr][dc] += h4[dr].f[dk] * p4[dk].f[dc];
            }
            #pragma unroll
            for (int dr = 0; dr < 4; ++dr) {
                float4 v; v.x = acc[dr][0]; v.y = acc[dr][1]; v.z = acc[dr][2]; v.w = acc[dr][3];
                *(float4*)&Aug[(i0 + dr) * AUGW + 64 + j0] = v;
            }
        }
        __syncthreads();

        // ---- Phase E: S lower = E * H^T + R (tid<136); P diag += Q (tid 136..199);
        //      reset convergence flags (tid 200)
        if (tid < 136) {
            const int i0 = 4 * Rlow, j0 = 4 * Clow;
            float acc[4][4];
            #pragma unroll
            for (int a = 0; a < 4; ++a)
                #pragma unroll
                for (int c = 0; c < 4; ++c) acc[a][c] = 0.f;
            #pragma unroll 8
            for (int c4 = 0; c4 < 16; ++c4) {
                F4 a4[4], b4[4];
                #pragma unroll
                for (int dr = 0; dr < 4; ++dr) a4[dr].v = *(const float4*)&Aug[(i0 + dr) * AUGW + 64 + 4 * c4];
                #pragma unroll
                for (int dc = 0; dc < 4; ++dc) b4[dc].v = *(const float4*)&Hs[(j0 + dc) * HW + 4 * c4];
                #pragma unroll
                for (int dr = 0; dr < 4; ++dr)
                    #pragma unroll
                    for (int dc = 0; dc < 4; ++dc)
                        #pragma unroll
                        for (int dk = 0; dk < 4; ++dk)
                            acc[dr][dc] += a4[dr].f[dk] * b4[dc].f[dk];
            }
            #pragma unroll
            for (int dr = 0; dr < 4; ++dr) {
                #pragma unroll
                for (int dc = 0; dc < 4; ++dc)
                    if (i0 + dr == j0 + dc) acc[dr][dc] += Rd[i0 + dr];
                float4 v; v.x = acc[dr][0]; v.y = acc[dr][1]; v.z = acc[dr][2]; v.w = acc[dr][3];
                *(float4*)&Aug[(i0 + dr) * AUGW + j0] = v;
            }
        } else if (tid < 200) {
            const int i = tid - 136;
            P[i * PW + i] += Qd[i];        // P becomes P_pred; read by phase G
        } else if (tid == 200) {
            flagI[0] = 0; flagI[1] = 0;    // reset for this step's final-phase atomics
        }
        __syncthreads();

        // ---- Panels: F1/F2 on wave 0 (readlane chains), incremental-G on tids 64..199,
        //      F3 trailing update on all threads.
        F4 gacc[4];
        #pragma unroll 1
        for (int p = 0; p < 4; ++p) {
            const int p0 = 16 * p;
            if (tid < 64) {
                // F1: panel factor (wave 0, wave-synchronous, registers + readlane)
                const int lane = tid;
                float st[16], lw[16], myrk = 0.f;
                if (lane >= p0) {
                    #pragma unroll
                    for (int q = 0; q < 4; ++q) {
                        F4 t4; t4.v = *(const float4*)&Aug[lane * AUGW + p0 + 4 * q];
                        st[4*q+0] = t4.f[0]; st[4*q+1] = t4.f[1]; st[4*q+2] = t4.f[2]; st[4*q+3] = t4.f[3];
                    }
                } else {
                    #pragma unroll
                    for (int q = 0; q < 16; ++q) st[q] = 0.f;
                }
                #pragma unroll
                for (int kr = 0; kr < 16; ++kr) {
                    const int k = p0 + kr;
                    float dk  = rl(st[kr], k);
                    float rkv = __builtin_amdgcn_rcpf(dk);   // ~1ulp; Riccati self-corrects
                    if (lane == k) myrk = rkv;
                    float coef = st[kr] * rkv;
                    coef = (lane > k) ? coef : 0.f;
                    lw[kr] = coef;
                    #pragma unroll
                    for (int jr = kr + 1; jr < 16; ++jr) {
                        float wjk = rl(st[kr], p0 + jr);
                        st[jr] -= coef * wjk;
                    }
                }
                if (lane >= p0) {
                    #pragma unroll
                    for (int q = 0; q < 4; ++q) {
                        float4 v; v.x = st[4*q+0]; v.y = st[4*q+1]; v.z = st[4*q+2]; v.w = st[4*q+3];
                        *(float4*)&Aug[lane * AUGW + p0 + 4 * q] = v;   // W (raw factored)
                    }
                    if (lane < p0 + 16) rk[lane] = myrk;
                }
                if (lane >= p0 + 16) {   // only trailing rows' L are ever read (by F3)
                    #pragma unroll
                    for (int q = 0; q < 4; ++q) {
                        float4 v; v.x = lw[4*q+0]; v.y = lw[4*q+1]; v.z = lw[4*q+2]; v.w = lw[4*q+3];
                        *(float4*)&LW(lane, 4 * q) = v;                 // true L factors
                    }
                }
                // F2: panel-row E/z triangular update (same wave, readlane)
                float ec[16], zr[16];
                #pragma unroll
                for (int r2 = 0; r2 < 16; ++r2) {
                    ec[r2] = Aug[(p0 + r2) * AUGW + 64 + lane];
                    zr[r2] = Aug[(p0 + r2) * AUGW + 128];
                }
                #pragma unroll
                for (int kp = 0; kp < 15; ++kp) {
                    #pragma unroll
                    for (int r2 = kp + 1; r2 < 16; ++r2) {
                        float L = rl(lw[kp], p0 + r2);
                        ec[r2] -= L * ec[kp];
                        zr[r2] -= L * zr[kp];
                    }
                }
                #pragma unroll
                for (int r2 = 0; r2 < 16; ++r2)
                    Aug[(p0 + r2) * AUGW + 64 + lane] = ec[r2];
                if (lane == 0) {
                    #pragma unroll
                    for (int r2 = 0; r2 < 16; ++r2)
                        Aug[(p0 + r2) * AUGW + 128] = zr[r2];
                }
            } else if (p > 0 && tid < 200) {
                // incremental G: chunk cp = p-1 (panel p-1's Etilde rows + rk are final)
                const int cp = p - 1;
                const int i0 = 4 * Rg, j0 = 4 * Cg;
                if (p == 1) {
                    #pragma unroll
                    for (int dr = 0; dr < 4; ++dr) gacc[dr].v = *(const float4*)&P[(i0 + dr) * PW + j0];
                }
                #pragma unroll
                for (int q = 0; q < 4; ++q) {
                    const int c4 = 4 * cp + q;
                    F4 rv; rv.v = *(const float4*)&rk[4 * c4];
                    F4 ea[4], eb[4];
                    #pragma unroll
                    for (int dk = 0; dk < 4; ++dk) ea[dk].v = *(const float4*)&Aug[(4 * c4 + dk) * AUGW + 64 + i0];
                    #pragma unroll
                    for (int dk = 0; dk < 4; ++dk) eb[dk].v = *(const float4*)&Aug[(4 * c4 + dk) * AUGW + 64 + j0];
                    #pragma unroll
                    for (int dk = 0; dk < 4; ++dk) {
                        float sc[4];
                        #pragma unroll
                        for (int dr = 0; dr < 4; ++dr) sc[dr] = ea[dk].f[dr] * rv.f[dk];
                        #pragma unroll
                        for (int dr = 0; dr < 4; ++dr)
                            #pragma unroll
                            for (int dc = 0; dc < 4; ++dc)
                                gacc[dr].f[dc] -= sc[dr] * eb[dk].f[dc];
                    }
                }
            }
            __syncthreads();

            // F3: rank-16 trailing update (empty for p==3)
            if (p < 3) {
                const int TS  = (p == 0) ? 78 : (p == 1) ? 36 : 10;
                const int rows = 48 - 16 * p;                 // trailing rows
                const int TE  = (rows / 4) * 17;
                const int tot = TS + TE;
                const int ofs = 4 * (p + 1);
                #pragma unroll 1
                for (int t = tid; t < tot; t += 256) {
                    int i0, Cb; bool isS;
                    if (t < TS) {
                        int rr = (int)((sqrtf(8.0f * (float)t + 1.0f) - 1.0f) * 0.5f);
                        if ((rr + 1) * (rr + 2) / 2 <= t) ++rr;
                        if (rr * (rr + 1) / 2 > t) --rr;
                        int cc = t - rr * (rr + 1) / 2;
                        i0 = 4 * (ofs + rr); Cb = 4 * (ofs + cc); isS = true;
                    } else {
                        int e2 = t - TS;
                        i0 = 4 * (ofs + e2 / 17); Cb = 64 + 4 * (e2 % 17); isS = false;
                    }
                    F4 acc[4];
                    #pragma unroll
                    for (int dr = 0; dr < 4; ++dr) acc[dr].v = *(const float4*)&Aug[(i0 + dr) * AUGW + Cb];
                    #pragma unroll
                    for (int c4 = 0; c4 < 4; ++c4) {
                        F4 a4[4];
                        #pragma unroll
                        for (int dr = 0; dr < 4; ++dr) a4[dr].v = *(const float4*)&LW(i0 + dr, 4 * c4);
                        if (isS) {
                            F4 b4[4];
                            #pragma unroll
                            for (int dc = 0; dc < 4; ++dc) b4[dc].v = *(const float4*)&Aug[(Cb + dc) * AUGW + p0 + 4 * c4];
                            #pragma unroll
                            for (int dr = 0; dr < 4; ++dr)
                                #pragma unroll
                                for (int dc = 0; dc < 4; ++dc)
                                    #pragma unroll
                                    for (int dk = 0; dk < 4; ++dk)
                                        acc[dr].f[dc] -= a4[dr].f[dk] * b4[dc].f[dk];
                        } else {
                            F4 b4[4];
                            #pragma unroll
                            for (int dk = 0; dk < 4; ++dk) b4[dk].v = *(const float4*)&Aug[(p0 + 4 * c4 + dk) * AUGW + Cb];
                            #pragma unroll
                            for (int dk = 0; dk < 4; ++dk)
                                #pragma unroll
                                for (int dr = 0; dr < 4; ++dr)
                                    #pragma unroll
                                    for (int dc = 0; dc < 4; ++dc)
                                        acc[dr].f[dc] -= a4[dr].f[dk] * b4[dk].f[dc];
                        }
                    }
                    #pragma unroll
                    for (int dr = 0; dr < 4; ++dr) *(float4*)&Aug[(i0 + dr) * AUGW + Cb] = acc[dr].v;
                }
                __syncthreads();
            }
        }

        // ---- Final phase: G-finish chunk 3 + P stores + out_ls + stats (tid 64..199);
        //      mu_post + out_mu (wave 0); stage next u/y (tid 200..223)
        const size_t o = (size_t)((s + 1) * NBS + b) * N;
        float tdmax = 0.f, tpmax = 0.f;
        if (tid >= 64 && tid < 200) {
            const int i0 = 4 * Rg, j0 = 4 * Cg;
            #pragma unroll
            for (int q = 0; q < 4; ++q) {
                const int c4 = 12 + q;
                F4 rv; rv.v = *(const float4*)&rk[4 * c4];
                F4 ea[4], eb[4];
                #pragma unroll
                for (int dk = 0; dk < 4; ++dk) ea[dk].v = *(const float4*)&Aug[(4 * c4 + dk) * AUGW + 64 + i0];
                #pragma unroll
                for (int dk = 0; dk < 4; ++dk) eb[dk].v = *(const float4*)&Aug[(4 * c4 + dk) * AUGW + 64 + j0];
                #pragma unroll
                for (int dk = 0; dk < 4; ++dk) {
                    float sc[4];
                    #pragma unroll
                    for (int dr = 0; dr < 4; ++dr) sc[dr] = ea[dk].f[dr] * rv.f[dk];
                    #pragma unroll
                    for (int dr = 0; dr < 4; ++dr)
                        #pragma unroll
                        for (int dc = 0; dc < 4; ++dc)
                            gacc[dr].f[dc] -= sc[dr] * eb[dk].f[dc];
                }
            }
            // stats vs P_pred (still in LDS, unmodified), then write
            #pragma unroll
            for (int dr = 0; dr < 4; ++dr) {
                F4 oldv; oldv.v = *(const float4*)&P[(i0 + dr) * PW + j0];
                #pragma unroll
                for (int dc = 0; dc < 4; ++dc) {
                    float d = gacc[dr].f[dc] - oldv.f[dc];
                    if (Rg == Cg && dr == dc) d += Qd[i0 + dr];
                    tdmax = fmaxf(tdmax, fabsf(d));
                    tpmax = fmaxf(tpmax, fabsf(gacc[dr].f[dc]));
                }
            }
            #pragma unroll
            for (int dr = 0; dr < 4; ++dr) *(float4*)&P[(i0 + dr) * PW + j0] = gacc[dr].v;
            if (Rg != Cg) {
                #pragma unroll
                for (int dc = 0; dc < 4; ++dc) {
                    float4 v; v.x = gacc[0].f[dc]; v.y = gacc[1].f[dc]; v.z = gacc[2].f[dc]; v.w = gacc[3].f[dc];
                    *(float4*)&P[(j0 + dc) * PW + i0] = v;
                }
            } else {
                #pragma unroll
                for (int dr = 0; dr < 4; ++dr)
                    out_ls[o + i0 + dr] = 0.5f * logf(gacc[dr].f[dr]);
            }
        } else if (tid < 64) {   // mu_post = mu_pred + E~^T (rk .* z~)  (wave 0)
            const int i = tid;
            wv[i] = rk[i] * Aug[i * AUGW + 128];
            float acc = mup[i];
            #pragma unroll
            for (int c4 = 0; c4 < 16; ++c4) {
                F4 wq; wq.v = *(const float4*)&wv[4 * c4];
                #pragma unroll
                for (int dk = 0; dk < 4; ++dk)
                    acc += Aug[(4 * c4 + dk) * AUGW + 64 + i] * wq.f[dk];
            }
            mu[i] = acc;
            out_mu[o + i] = acc;
        }
        if (tid >= 200 && tid < 208) {          // stage u for s+1
            int q = tid - 200;
            *(float4*)&uvec[4 * q] = *(const float4*)&ext[(size_t)((s + 1) * NBS + b) * NI + 4 * q];
        }
        if (tid >= 208 && tid < 224 && s < L_SEQ - 2) {   // stage y for s+1 (obs row s+2)
            int q = tid - 208;
            *(float4*)&yv[4 * q] = *(const float4*)&obs[(size_t)((s + 2) * NBS + b) * N + 4 * q];
        }
        // block-wide max reduce of convergence stats (12 shfl + 2 atomics/wave)
        #pragma unroll
        for (int off = 32; off; off >>= 1) {
            tdmax = fmaxf(tdmax, __shfl_xor(tdmax, off, 64));
            tpmax = fmaxf(tpmax, __shfl_xor(tpmax, off, 64));
        }
        if ((tid & 63) == 0) {
            atomicMax(&flagI[0], __float_as_int(tdmax));
            atomicMax(&flagI[1], __float_as_int(tpmax));
        }
        __syncthreads();

        // uniform convergence decision (flags reset next step in phase E, after D-barrier)
        {
            float dm = __int_as_float(flagI[0]);
            float pm = __int_as_float(flagI[1]);
            bool conv = (s >= CONV_MINS) && (dm <= CONV_TAU * pm);
            streak = conv ? (streak + 1) : 0;
            if (streak >= 2) { sb = s + 1; break; }
        }
    }

    // ---------------- converged tail: frozen covariance, 1 barrier/step ----------------
    if (sb > 0) {
        // one-time (1/3): Kg = P_post * H^T * R^{-1} -> Aug E-panel; lsc = frozen out_ls
        {
            const int i0 = 4 * ty, j0 = 4 * tx;
            float acc[4][4];
            #pragma unroll
            for (int a = 0; a < 4; ++a)
                #pragma unroll
                for (int c = 0; c < 4; ++c) acc[a][c] = 0.f;
            #pragma unroll 8
            for (int c4 = 0; c4 < 16; ++c4) {
                F4 a4[4], b4[4];
                #pragma unroll
                for (int dr = 0; dr < 4; ++dr) a4[dr].v = *(const float4*)&P[(i0 + dr) * PW + 4 * c4];
                #pragma unroll
                for (int dc = 0; dc < 4; ++dc) b4[dc].v = *(const float4*)&Hs[(j0 + dc) * HW + 4 * c4];
                #pragma unroll
                for (int dr = 0; dr < 4; ++dr)
                    #pragma unroll
                    for (int dc = 0; dc < 4; ++dc)
                        #pragma unroll
                        for (int dk = 0; dk < 4; ++dk)
                            acc[dr][dc] += a4[dr].f[dk] * b4[dc].f[dk];
            }
            float ri[4];
            #pragma unroll
            for (int dc = 0; dc < 4; ++dc) ri[dc] = 1.0f / Rd[j0 + dc];
            #pragma unroll
            for (int dr = 0; dr < 4; ++dr) {
                float4 v; v.x = acc[dr][0]*ri[0]; v.y = acc[dr][1]*ri[1];
                          v.z = acc[dr][2]*ri[2]; v.w = acc[dr][3]*ri[3];
                *(float4*)&Aug[(i0 + dr) * AUGW + 64 + j0] = v;
            }
            if (tid < 64) lsc[tid] = 0.5f * logf(P[tid * PW + tid]);
        }
        __syncthreads();

        // one-time (2/3): M = I - Kg*H -> Aug S-panel (cols 0..63)
        {
            const int i0 = 4 * ty, j0 = 4 * tx;
            float acc[4][4];
            #pragma unroll
            for (int dr = 0; dr < 4; ++dr)
                #pragma unroll
                for (int dc = 0; dc < 4; ++dc)
                    acc[dr][dc] = (i0 + dr == j0 + dc) ? 1.f : 0.f;
            #pragma unroll 8
            for (int c4 = 0; c4 < 16; ++c4) {
                F4 kg4[4], h4[4];
                #pragma unroll
                for (int dr = 0; dr < 4; ++dr) kg4[dr].v = *(const float4*)&Aug[(i0 + dr) * AUGW + 64 + 4 * c4];
                #pragma unroll
                for (int dk = 0; dk < 4; ++dk) h4[dk].v = *(const float4*)&Hs[(4 * c4 + dk) * HW + j0];
                #pragma unroll
                for (int dk = 0; dk < 4; ++dk)
                    #pragma unroll
                    for (int dr = 0; dr < 4; ++dr)
                        #pragma unroll
                        for (int dc = 0; dc < 4; ++dc)
                            acc[dr][dc] -= kg4[dr].f[dk] * h4[dk].f[dc];
            }
            #pragma unroll
            for (int dr = 0; dr < 4; ++dr) {
                float4 v; v.x = acc[dr][0]; v.y = acc[dr][1]; v.z = acc[dr][2]; v.w = acc[dr][3];
                *(float4*)&Aug[(i0 + dr) * AUGW + j0] = v;
            }
        }
        __syncthreads();

        // one-time (3/3): Cu = M*B -> P rows (Cut[k][i] = P[k*PW+i], k<32);
        //                 copy u/y into parity-1 shadows (mup/wv)
        {
            const int i = tid & 63, kb = tid >> 6;    // kb in 0..3, 8 k's each
            float cu[8];
            #pragma unroll
            for (int q = 0; q < 8; ++q) {
                const int k = 8 * kb + q;
                float acc = 0.f;
                #pragma unroll 8
                for (int c4 = 0; c4 < 16; ++c4) {
                    F4 m4; m4.v = *(const float4*)&Aug[i * AUGW + 4 * c4];
                    F4 b4; b4.v = *(const float4*)&Bt[k * 64 + 4 * c4];
                    acc += m4.f[0]*b4.f[0] + m4.f[1]*b4.f[1] + m4.f[2]*b4.f[2] + m4.f[3]*b4.f[3];
                }
                cu[q] = acc;
            }
            #pragma unroll
            for (int q = 0; q < 8; ++q) P[(8 * kb + q) * PW + i] = cu[q];
            if (tid < 8)  *(float4*)&mup[4 * tid] = *(const float4*)&uvec[4 * tid];
            if (tid >= 8 && tid < 24) { int q = tid - 8; *(float4*)&wv[4 * q] = *(const float4*)&yv[4 * q]; }
        }
        __syncthreads();

        // tail loop: mu' = M*mu + Cu*u + Kg*y ; one barrier per step
        #pragma unroll 1
        for (int s2 = sb; s2 < L_SEQ - 1; ++s2) {
            const size_t o2 = (size_t)((s2 + 1) * NBS + b) * N;
            const int par = s2 & 1;
            float* ucur = par ? mup : uvec;
            float* ynow = par ? wv  : yv;
            float* unxt = par ? uvec : mup;
            float* ynxt = par ? yv  : wv;
            if (tid < 64) {
                const int i = tid;
                float acc = 0.f;
                #pragma unroll
                for (int c4 = 0; c4 < 16; ++c4) {
                    F4 m4;  m4.v  = *(const float4*)&Aug[i * AUGW + 4 * c4];
                    F4 kg4; kg4.v = *(const float4*)&Aug[i * AUGW + 64 + 4 * c4];
                    F4 mv;  mv.v  = *(const float4*)&mu[4 * c4];
                    F4 yv4; yv4.v = *(const float4*)&ynow[4 * c4];
                    #pragma unroll
                    for (int t = 0; t < 4; ++t)
                        acc += m4.f[t] * mv.f[t] + kg4.f[t] * yv4.f[t];
                }
                #pragma unroll
                for (int k = 0; k < NI; ++k) acc += P[k * PW + i] * ucur[k];
                mu[i] = acc;
                out_mu[o2 + i] = acc;
                out_ls[o2 + i] = lsc[i];
            } else if (tid < 72) {                       // stage u for s2+1
                int q = tid - 64;
                *(float4*)&unxt[4 * q] = *(const float4*)&ext[(size_t)((s2 + 1) * NBS + b) * NI + 4 * q];
            } else if (tid < 88 && s2 < L_SEQ - 2) {     // stage y for s2+1 (obs row s2+2)
                int q = tid - 72;
                *(float4*)&ynxt[4 * q] = *(const float4*)&obs[(size_t)((s2 + 2) * NBS + b) * N + 4 * q];
            }
            __syncthreads();
        }
    }
}

extern "C" void kernel_launch(void* const* d_in, const int* in_sizes, int n_in,
                              void* d_out, int out_size, void* d_ws, size_t ws_size,
                              hipStream_t stream) {
    const float* ext = (const float*)d_in[0];
    const float* obs = (const float*)d_in[1];
    const float* mu0 = (const float*)d_in[2];
    const float* sg0 = (const float*)d_in[3];
    const float* lsg = (const float*)d_in[4];
    const float* Bm  = (const float*)d_in[5];
    const float* Hm  = (const float*)d_in[6];
    const float* ldl = (const float*)d_in[7];
    float* out_mu = (float*)d_out;
    float* out_ls = out_mu + (size_t)L_SEQ * NBS * N;

    size_t smem = (size_t)SM_FLOATS * sizeof(float);   // 78992 B
    hipFuncSetAttribute(reinterpret_cast<const void*>(akf8),
                        hipFuncAttributeMaxDynamicSharedMemorySize, (int)smem);

    akf8<<<dim3(NBS), dim3(256), smem, stream>>>(
        ext, obs, mu0, sg0, lsg, Bm, Hm, ldl, out_mu, out_ls);
}